// Round 1
// baseline (745.626 us; speedup 1.0000x reference)
//
#include <hip/hip_runtime.h>
#include <hip/hip_bf16.h>

#define NB 8
#define NC 128
#define NHW 128
#define NSP (NHW*NHW)     // 16384
#define SLOPE 0.2f
#define EPSN 1e-12f

// ---------- weight layout transforms ----------
// conv1_w [o][i][kh][kw] -> wt1 [kh][i][kw][o]
__global__ void transpose_conv1_w(const float* __restrict__ w, float* __restrict__ wt) {
    int idx = blockIdx.x * 256 + threadIdx.x;          // 128*128*9 = 147456
    if (idx >= 128 * 128 * 9) return;
    int kw = idx % 3; int t = idx / 3;
    int kh = t % 3;   t /= 3;
    int i  = t % 128; int o = t / 128;
    wt[(((kh * 128 + i) * 3) + kw) * 128 + o] = w[idx];
}

// w [o][i] -> wt [i][o]
__global__ void transpose_1x1_w(const float* __restrict__ w, float* __restrict__ wt) {
    int idx = blockIdx.x * 256 + threadIdx.x;          // 16384
    if (idx >= 128 * 128) return;
    int i = idx % 128, o = idx / 128;
    wt[i * 128 + o] = w[idx];
}

// ---------- attention: Gram matrix per (b,head) ----------
__global__ __launch_bounds__(256) void gram_kernel(const float* __restrict__ x1,
                                                   float* __restrict__ G) {
    int bh = blockIdx.x;                                // b*16 + head
    const float* base = x1 + (size_t)bh * 8 * NSP;
    float acc[8][8];
#pragma unroll
    for (int c = 0; c < 8; c++)
#pragma unroll
        for (int d = 0; d < 8; d++) acc[c][d] = 0.f;

    for (int n = threadIdx.x; n < NSP; n += 256) {
        float v[8];
#pragma unroll
        for (int c = 0; c < 8; c++) v[c] = base[c * NSP + n];
#pragma unroll
        for (int c = 0; c < 8; c++)
#pragma unroll
            for (int d = 0; d < 8; d++)
                acc[c][d] = fmaf(v[c], v[d], acc[c][d]);
    }
    // wave(64)-level shuffle reduce
#pragma unroll
    for (int c = 0; c < 8; c++)
#pragma unroll
        for (int d = 0; d < 8; d++)
            for (int off = 32; off > 0; off >>= 1)
                acc[c][d] += __shfl_down(acc[c][d], off);

    __shared__ float red[4][64];
    int wv = threadIdx.x >> 6;
    if ((threadIdx.x & 63) == 0) {
#pragma unroll
        for (int c = 0; c < 8; c++)
#pragma unroll
            for (int d = 0; d < 8; d++) red[wv][c * 8 + d] = acc[c][d];
    }
    __syncthreads();
    if (threadIdx.x < 64)
        G[bh * 64 + threadIdx.x] =
            red[0][threadIdx.x] + red[1][threadIdx.x] + red[2][threadIdx.x] + red[3][threadIdx.x];
}

// ---------- softmax over 8x8 attention logits ----------
__global__ void softmax_kernel(const float* __restrict__ G, const float* __restrict__ temp,
                               float* __restrict__ attn) {
    int bh = blockIdx.x; int h = bh & 15;
    int t = threadIdx.x;                   // 64 threads: c*8+d
    int c = t >> 3, d = t & 7;
    const float* g = G + bh * 64;
    float nc = fmaxf(sqrtf(g[c * 8 + c]), EPSN);
    float nd = fmaxf(sqrtf(g[d * 8 + d]), EPSN);
    float a = g[t] / (nc * nd) * temp[h];
    float m = a;
#pragma unroll
    for (int off = 4; off > 0; off >>= 1) m = fmaxf(m, __shfl_xor(m, off));
    float e = __expf(a - m);
    float s = e;
#pragma unroll
    for (int off = 4; off > 0; off >>= 1) s += __shfl_xor(s, off);
    attn[bh * 64 + t] = e / s;
}

// ---------- out = attn @ v ----------
__global__ __launch_bounds__(256) void av_kernel(const float* __restrict__ x2,
                                                 const float* __restrict__ attn,
                                                 float* __restrict__ y) {
    int bh = blockIdx.y;
    int n = blockIdx.x * 256 + threadIdx.x;
    __shared__ float a[64];
    if (threadIdx.x < 64) a[threadIdx.x] = attn[bh * 64 + threadIdx.x];
    __syncthreads();
    const float* vb = x2 + (size_t)bh * 8 * NSP + n;
    float v[8];
#pragma unroll
    for (int d = 0; d < 8; d++) v[d] = vb[d * NSP];
    float* yb = y + (size_t)bh * 8 * NSP + n;
#pragma unroll
    for (int c = 0; c < 8; c++) {
        float s = 0.f;
#pragma unroll
        for (int d = 0; d < 8; d++) s = fmaf(a[c * 8 + d], v[d], s);
        yb[c * NSP] = s;
    }
}

// ---------- conv1: 3x3 zero-pad + bias + LeakyReLU ----------
// block = one output row (b,h), all 128 out channels. 4 waves, each owns 32 o-chans.
// lane covers w and w+64. Weights fetched via wave-uniform address -> scalar loads.
__global__ __launch_bounds__(256) void conv1_kernel(const float* __restrict__ y,
                                                    const float* __restrict__ wt1, // [kh][i][kw][o]
                                                    const float* __restrict__ b1,
                                                    float* __restrict__ h1) {
    int bh = blockIdx.x;              // b*128 + h
    int b = bh >> 7, h = bh & 127;
    int lane = threadIdx.x & 63;
    int og = __builtin_amdgcn_readfirstlane((int)(threadIdx.x >> 6)) * 32;

    __shared__ float xs[16][3][132];  // 16 in-chans, rows h-1..h+1, cols w=-1..130

    float acc[32][2];
#pragma unroll
    for (int o = 0; o < 32; ++o) { acc[o][0] = 0.f; acc[o][1] = 0.f; }

    for (int ic = 0; ic < 128; ic += 16) {
        __syncthreads();
        for (int idx = threadIdx.x; idx < 16 * 3 * 132; idx += 256) {
            int i = idx / (3 * 132);
            int rem = idx % (3 * 132);
            int r = rem / 132;
            int col = rem % 132;      // input w = col-1
            int hh = h + r - 1;
            int w = col - 1;
            float v = 0.f;
            if (hh >= 0 && hh < 128 && w >= 0 && w < 128)
                v = y[((size_t)(b * 128 + ic + i) * 128 + hh) * 128 + w];
            xs[i][r][col] = v;
        }
        __syncthreads();

        for (int i = 0; i < 16; ++i) {
#pragma unroll
            for (int r = 0; r < 3; ++r) {
                float xa0 = xs[i][r][lane];
                float xa1 = xs[i][r][lane + 1];
                float xa2 = xs[i][r][lane + 2];
                float xb0 = xs[i][r][lane + 64];
                float xb1 = xs[i][r][lane + 65];
                float xb2 = xs[i][r][lane + 66];
                const float* wr = wt1 + ((size_t)(r * 128 + ic + i) * 3) * 128 + og;
#pragma unroll
                for (int o = 0; o < 32; ++o) {
                    float w0 = wr[o];
                    float w1 = wr[128 + o];
                    float w2 = wr[256 + o];
                    acc[o][0] = fmaf(xa0, w0, acc[o][0]);
                    acc[o][0] = fmaf(xa1, w1, acc[o][0]);
                    acc[o][0] = fmaf(xa2, w2, acc[o][0]);
                    acc[o][1] = fmaf(xb0, w0, acc[o][1]);
                    acc[o][1] = fmaf(xb1, w1, acc[o][1]);
                    acc[o][1] = fmaf(xb2, w2, acc[o][1]);
                }
            }
        }
    }
#pragma unroll
    for (int o = 0; o < 32; ++o) {
        int oc = og + o;
        float bv = b1[oc];
        float v0 = acc[o][0] + bv;
        float v1 = acc[o][1] + bv;
        v0 = v0 >= 0.f ? v0 : SLOPE * v0;
        v1 = v1 >= 0.f ? v1 : SLOPE * v1;
        size_t base = ((size_t)(b * 128 + oc) * 128 + h) * 128;
        h1[base + lane] = v0;
        h1[base + lane + 64] = v1;
    }
}

// ---------- generic 1x1 conv (K=128), optional elementwise add ----------
__global__ __launch_bounds__(256) void conv1x1_kernel(const float* __restrict__ x,
                                                      const float* __restrict__ wt, // [i][o]
                                                      const float* __restrict__ bias,
                                                      const float* __restrict__ add,
                                                      float* __restrict__ out) {
    int pb = blockIdx.x;              // 2048 blocks x 64 positions
    int b = pb >> 8;
    int n0 = (pb & 255) << 6;
    int lane = threadIdx.x & 63;
    int og = __builtin_amdgcn_readfirstlane((int)(threadIdx.x >> 6)) * 32;

    __shared__ float xs[128][64];
    for (int idx = threadIdx.x; idx < 128 * 64; idx += 256) {
        int i = idx >> 6, p = idx & 63;
        xs[i][p] = x[(size_t)(b * 128 + i) * NSP + n0 + p];
    }
    __syncthreads();

    float acc[32];
#pragma unroll
    for (int o = 0; o < 32; o++) acc[o] = 0.f;
    for (int i = 0; i < 128; ++i) {
        float xv = xs[i][lane];
        const float* wr = wt + i * 128 + og;
#pragma unroll
        for (int o = 0; o < 32; o++) acc[o] = fmaf(xv, wr[o], acc[o]);
    }
#pragma unroll
    for (int o = 0; o < 32; o++) {
        int oc = og + o;
        size_t oidx = (size_t)(b * 128 + oc) * NSP + n0 + lane;
        float v = acc[o] + bias[oc];
        if (add) v += add[oidx];
        out[oidx] = v;
    }
}

// ---------- depthwise 3x3 reflect-pad + bias + LeakyReLU, out += result ----------
__global__ __launch_bounds__(256) void dw_kernel(const float* __restrict__ h2,
                                                 const float* __restrict__ dww,
                                                 const float* __restrict__ dwb,
                                                 float* __restrict__ out) {
    size_t idx = (size_t)blockIdx.x * 256 + threadIdx.x;   // B*C*N = 16777216 exact
    int w = (int)(idx & 127);
    int hh = (int)((idx >> 7) & 127);
    int bc = (int)(idx >> 14);
    int c = bc & 127;
    const float* src = h2 + ((size_t)bc << 14);
    float s = dwb[c];
#pragma unroll
    for (int kh = 0; kh < 3; kh++) {
        int ih = hh + kh - 1;
        ih = ih < 0 ? 1 : (ih > 127 ? 126 : ih);
#pragma unroll
        for (int kw = 0; kw < 3; kw++) {
            int iw = w + kw - 1;
            iw = iw < 0 ? 1 : (iw > 127 ? 126 : iw);
            s = fmaf(src[ih * 128 + iw], dww[c * 9 + kh * 3 + kw], s);
        }
    }
    s = s >= 0.f ? s : SLOPE * s;
    out[idx] += s;
}

extern "C" void kernel_launch(void* const* d_in, const int* in_sizes, int n_in,
                              void* d_out, int out_size, void* d_ws, size_t ws_size,
                              hipStream_t stream) {
    const float* x1   = (const float*)d_in[0];
    const float* x2   = (const float*)d_in[1];
    const float* temp = (const float*)d_in[2];
    const float* c1w  = (const float*)d_in[3];
    const float* c1b  = (const float*)d_in[4];
    const float* c2w  = (const float*)d_in[5];
    const float* c2b  = (const float*)d_in[6];
    const float* dww  = (const float*)d_in[7];
    const float* dwb  = (const float*)d_in[8];
    const float* scw  = (const float*)d_in[9];
    const float* scb  = (const float*)d_in[10];
    float* out = (float*)d_out;
    char* ws = (char*)d_ws;

    float* G    = (float*)(ws);                    // 32 KB
    float* attn = (float*)(ws + (32 << 10));       // 32 KB
    float* wt1  = (float*)(ws + (64 << 10));       // 576 KB
    float* wt2  = (float*)(ws + (704 << 10));      // 64 KB
    float* wtsc = (float*)(ws + (768 << 10));      // 64 KB
    float* y    = (float*)(ws + ((size_t)1 << 20));   // 64 MiB  (later reused as h2)
    float* h1   = (float*)(ws + ((size_t)65 << 20));  // 64 MiB

    transpose_conv1_w<<<576, 256, 0, stream>>>(c1w, wt1);
    transpose_1x1_w<<<64, 256, 0, stream>>>(c2w, wt2);
    transpose_1x1_w<<<64, 256, 0, stream>>>(scw, wtsc);

    gram_kernel<<<128, 256, 0, stream>>>(x1, G);
    softmax_kernel<<<128, 64, 0, stream>>>(G, temp, attn);
    av_kernel<<<dim3(64, 128), 256, 0, stream>>>(x2, attn, y);

    conv1_kernel<<<1024, 256, 0, stream>>>(y, wt1, c1b, h1);          // h1 = leaky(conv3x3(y))
    conv1x1_kernel<<<2048, 256, 0, stream>>>(y, wtsc, scb, x1, out);  // out = sc(y) + x1 (y dead after)
    conv1x1_kernel<<<2048, 256, 0, stream>>>(h1, wt2, c2b, nullptr, y); // h2 = conv2(h1) -> reuse y
    dw_kernel<<<65536, 256, 0, stream>>>(y, dww, dwb, out);           // out += leaky(dw(h2))
}

// Round 2
// 384.530 us; speedup vs baseline: 1.9391x; 1.9391x over previous
//
#include <hip/hip_runtime.h>
#include <hip/hip_bf16.h>

typedef __attribute__((ext_vector_type(8))) short short8;
typedef __attribute__((ext_vector_type(4))) float f32x4;

#define NB 8
#define NC 128
#define NHW 128
#define NSP (NHW*NHW)     // 16384
#define SLOPE 0.2f
#define EPSN 1e-12f

static __device__ __forceinline__ unsigned short f2bf(float f) {
    __hip_bfloat16 h = __float2bfloat16(f);
    return *reinterpret_cast<unsigned short*>(&h);
}

// ---------- weight prep ----------
// conv1_w [o][i][kh][kw] fp32 -> wb1 [tap=kh*3+kw][o][i] bf16 (i contiguous)
__global__ void prep_wb1(const float* __restrict__ w, __hip_bfloat16* __restrict__ wb) {
    int idx = blockIdx.x * 256 + threadIdx.x;          // 128*128*9 = 147456
    if (idx >= 128 * 128 * 9) return;
    int kw = idx % 3; int t = idx / 3;
    int kh = t % 3;   t /= 3;
    int i  = t % 128; int o = t / 128;
    wb[((size_t)(kh * 3 + kw) * 128 + o) * 128 + i] = __float2bfloat16(w[idx]);
}

// w [o][i] -> wt [i][o] fp32
__global__ void transpose_1x1_w(const float* __restrict__ w, float* __restrict__ wt) {
    int idx = blockIdx.x * 256 + threadIdx.x;          // 16384
    if (idx >= 128 * 128) return;
    int i = idx % 128, o = idx / 128;
    wt[i * 128 + o] = w[idx];
}

// ---------- attention: Gram matrix per (b,head) ----------
__global__ __launch_bounds__(256) void gram_kernel(const float* __restrict__ x1,
                                                   float* __restrict__ G) {
    int bh = blockIdx.x;                                // b*16 + head
    const float* base = x1 + (size_t)bh * 8 * NSP;
    float acc[8][8];
#pragma unroll
    for (int c = 0; c < 8; c++)
#pragma unroll
        for (int d = 0; d < 8; d++) acc[c][d] = 0.f;

    for (int n = threadIdx.x; n < NSP; n += 256) {
        float v[8];
#pragma unroll
        for (int c = 0; c < 8; c++) v[c] = base[c * NSP + n];
#pragma unroll
        for (int c = 0; c < 8; c++)
#pragma unroll
            for (int d = 0; d < 8; d++)
                acc[c][d] = fmaf(v[c], v[d], acc[c][d]);
    }
#pragma unroll
    for (int c = 0; c < 8; c++)
#pragma unroll
        for (int d = 0; d < 8; d++)
            for (int off = 32; off > 0; off >>= 1)
                acc[c][d] += __shfl_down(acc[c][d], off);

    __shared__ float red[4][64];
    int wv = threadIdx.x >> 6;
    if ((threadIdx.x & 63) == 0) {
#pragma unroll
        for (int c = 0; c < 8; c++)
#pragma unroll
            for (int d = 0; d < 8; d++) red[wv][c * 8 + d] = acc[c][d];
    }
    __syncthreads();
    if (threadIdx.x < 64)
        G[bh * 64 + threadIdx.x] =
            red[0][threadIdx.x] + red[1][threadIdx.x] + red[2][threadIdx.x] + red[3][threadIdx.x];
}

// ---------- softmax over 8x8 attention logits ----------
__global__ void softmax_kernel(const float* __restrict__ G, const float* __restrict__ temp,
                               float* __restrict__ attn) {
    int bh = blockIdx.x; int h = bh & 15;
    int t = threadIdx.x;                   // 64 threads: c*8+d
    int c = t >> 3, d = t & 7;
    const float* g = G + bh * 64;
    float nc = fmaxf(sqrtf(g[c * 8 + c]), EPSN);
    float nd = fmaxf(sqrtf(g[d * 8 + d]), EPSN);
    float a = g[t] / (nc * nd) * temp[h];
    float m = a;
#pragma unroll
    for (int off = 4; off > 0; off >>= 1) m = fmaxf(m, __shfl_xor(m, off));
    float e = __expf(a - m);
    float s = e;
#pragma unroll
    for (int off = 4; off > 0; off >>= 1) s += __shfl_xor(s, off);
    attn[bh * 64 + t] = e / s;
}

// ---------- y_t = attn @ v, written NHWC bf16 ----------
__global__ __launch_bounds__(256) void av_kernel(const float* __restrict__ x2,
                                                 const float* __restrict__ attn,
                                                 __hip_bfloat16* __restrict__ yt) {
    int bh = blockIdx.y;                 // b*16 + head
    int b = bh >> 4, head = bh & 15;
    int n = blockIdx.x * 256 + threadIdx.x;
    __shared__ float a[64];
    if (threadIdx.x < 64) a[threadIdx.x] = attn[bh * 64 + threadIdx.x];
    __syncthreads();
    const float* vb = x2 + (size_t)bh * 8 * NSP + n;
    float v[8];
#pragma unroll
    for (int d = 0; d < 8; d++) v[d] = vb[d * NSP];
    unsigned int pk[4];
#pragma unroll
    for (int c = 0; c < 8; c += 2) {
        float s0 = 0.f, s1 = 0.f;
#pragma unroll
        for (int d = 0; d < 8; d++) {
            s0 = fmaf(a[c * 8 + d], v[d], s0);
            s1 = fmaf(a[(c + 1) * 8 + d], v[d], s1);
        }
        pk[c >> 1] = (unsigned int)f2bf(s0) | ((unsigned int)f2bf(s1) << 16);
    }
    uint4 st; st.x = pk[0]; st.y = pk[1]; st.z = pk[2]; st.w = pk[3];
    *reinterpret_cast<uint4*>(yt + ((size_t)b * NSP + n) * 128 + head * 8) = st;
}

// ---------- conv1: 3x3 zero-pad, bias, LeakyReLU — MFMA implicit GEMM ----------
// Block = (b, output row h). M=128 positions (w), N=128 out-ch, K=1152 (9 taps x 128 ic).
// LDS stages input rows h-1..h+1 x cols -1..130 x 64 channels (one ic-half), XOR-swizzled.
// 4 waves, each owns 4 m-frags x 4 n-frags of 16x16.
__global__ __launch_bounds__(256) void conv1_mfma(const __hip_bfloat16* __restrict__ yt,
                                                  const __hip_bfloat16* __restrict__ wb,
                                                  const float* __restrict__ b1,
                                                  float* __restrict__ h1) {
    __shared__ uint4 smem[3168];          // [r:3][col:132][granule:8] of 16B (8 bf16 chans)
    int blk = blockIdx.x;                 // b*128 + h
    int b = blk >> 7, h = blk & 127;
    int tid = threadIdx.x;
    int lane = tid & 63;
    int wid = tid >> 6;
    int wm = wid >> 1, wn = wid & 1;      // wave grid 2x2 over (m,n)
    int l15 = lane & 15;
    int lk = lane >> 4;                   // 0..3

    f32x4 acc[4][4];
#pragma unroll
    for (int a = 0; a < 4; a++)
#pragma unroll
        for (int c = 0; c < 4; c++) acc[a][c] = (f32x4){0.f, 0.f, 0.f, 0.f};

    for (int half = 0; half < 2; ++half) {
        __syncthreads();
        // stage: 3 rows x 132 cols x 8 granules = 3168 16B chunks
        for (int idx = tid; idx < 3168; idx += 256) {
            int chunk = idx & 7;
            int colr = idx >> 3;
            int col = colr % 132;
            int r = colr / 132;
            int hh = h + r - 1;
            int w = col - 1;
            uint4 v = make_uint4(0u, 0u, 0u, 0u);
            if ((unsigned)hh < 128u && (unsigned)w < 128u)
                v = *reinterpret_cast<const uint4*>(
                    yt + (((size_t)(b * 128 + hh)) * 128 + w) * 128 + half * 64 + chunk * 8);
            smem[r * 1056 + col * 8 + (chunk ^ (col & 7))] = v;
        }
        __syncthreads();

        for (int t = 0; t < 9; ++t) {
            int kh = t / 3, kw = t % 3;
            // B row base for this wave: o = wn*64 + l15 (+c2*16), k base = half*64 + lk*8 (+icc*32)
            const __hip_bfloat16* wrow = wb + ((size_t)t * 128 + wn * 64 + l15) * 128 + half * 64 + lk * 8;
#pragma unroll
            for (int icc = 0; icc < 2; ++icc) {
                short8 bfr[4];
#pragma unroll
                for (int c = 0; c < 4; ++c)
                    bfr[c] = *reinterpret_cast<const short8*>(wrow + c * 2048 + icc * 32);
                short8 afr[4];
#pragma unroll
                for (int a = 0; a < 4; ++a) {
                    int col = (wm * 4 + a) * 16 + l15 + kw;   // w + kw, shifted by +1 pad
                    int chunk = icc * 4 + lk;
                    afr[a] = *reinterpret_cast<const short8*>(
                        &smem[kh * 1056 + col * 8 + (chunk ^ (col & 7))]);
                }
#pragma unroll
                for (int a = 0; a < 4; ++a)
#pragma unroll
                    for (int c = 0; c < 4; ++c)
                        acc[a][c] = __builtin_amdgcn_mfma_f32_16x16x32_bf16(
                            afr[a], bfr[c], acc[a][c], 0, 0, 0);
            }
        }
    }

    // epilogue: bias + LeakyReLU, store fp32 NCHW. C/D: col(o)=lane&15, row(w)=lk*4+reg.
#pragma unroll
    for (int c = 0; c < 4; ++c) {
        int o = wn * 64 + c * 16 + l15;
        float bv = b1[o];
        size_t obase = ((size_t)(b * 128 + o) * 128 + h) * 128;
#pragma unroll
        for (int a = 0; a < 4; ++a) {
            int w0 = (wm * 4 + a) * 16 + lk * 4;
            float4 st;
            float v0 = acc[a][c][0] + bv; st.x = v0 >= 0.f ? v0 : SLOPE * v0;
            float v1 = acc[a][c][1] + bv; st.y = v1 >= 0.f ? v1 : SLOPE * v1;
            float v2 = acc[a][c][2] + bv; st.z = v2 >= 0.f ? v2 : SLOPE * v2;
            float v3 = acc[a][c][3] + bv; st.w = v3 >= 0.f ? v3 : SLOPE * v3;
            *reinterpret_cast<float4*>(h1 + obase + w0) = st;
        }
    }
}

// ---------- 1x1 conv, fp32 NCHW input (used for conv2) ----------
__global__ __launch_bounds__(256) void conv1x1_kernel(const float* __restrict__ x,
                                                      const float* __restrict__ wt, // [i][o]
                                                      const float* __restrict__ bias,
                                                      const float* __restrict__ add,
                                                      float* __restrict__ out) {
    int pb = blockIdx.x;              // 2048 blocks x 64 positions
    int b = pb >> 8;
    int n0 = (pb & 255) << 6;
    int lane = threadIdx.x & 63;
    int og = __builtin_amdgcn_readfirstlane((int)(threadIdx.x >> 6)) * 32;

    __shared__ float xs[128][64];
    for (int idx = threadIdx.x; idx < 128 * 64; idx += 256) {
        int i = idx >> 6, p = idx & 63;
        xs[i][p] = x[(size_t)(b * 128 + i) * NSP + n0 + p];
    }
    __syncthreads();

    float acc[32];
#pragma unroll
    for (int o = 0; o < 32; o++) acc[o] = 0.f;
    for (int i = 0; i < 128; ++i) {
        float xv = xs[i][lane];
        const float* wr = wt + i * 128 + og;
#pragma unroll
        for (int o = 0; o < 32; o++) acc[o] = fmaf(xv, wr[o], acc[o]);
    }
#pragma unroll
    for (int o = 0; o < 32; o++) {
        int oc = og + o;
        size_t oidx = (size_t)(b * 128 + oc) * NSP + n0 + lane;
        float v = acc[o] + bias[oc];
        if (add) v += add[oidx];
        out[oidx] = v;
    }
}

// ---------- 1x1 conv, NHWC bf16 input (used for shortcut) ----------
__global__ __launch_bounds__(256) void conv1x1_bf(const __hip_bfloat16* __restrict__ xt,
                                                  const float* __restrict__ wt, // [i][o]
                                                  const float* __restrict__ bias,
                                                  const float* __restrict__ add,
                                                  float* __restrict__ out) {
    int pb = blockIdx.x;              // b*256 + posblock; 64 positions each
    int b = pb >> 8;
    int n0 = (pb & 255) << 6;
    int lane = threadIdx.x & 63;
    int og = __builtin_amdgcn_readfirstlane((int)(threadIdx.x >> 6)) * 32;

    __shared__ float xs[64][129];
    for (int idx = threadIdx.x; idx < 64 * 16; idx += 256) {
        int p = idx >> 4, ch = (idx & 15) * 8;
        uint4 raw = *reinterpret_cast<const uint4*>(xt + ((size_t)b * NSP + n0 + p) * 128 + ch);
        const unsigned short* u = reinterpret_cast<const unsigned short*>(&raw);
#pragma unroll
        for (int j = 0; j < 8; ++j)
            xs[p][ch + j] = __uint_as_float((unsigned int)u[j] << 16);
    }
    __syncthreads();

    float acc[32];
#pragma unroll
    for (int o = 0; o < 32; o++) acc[o] = 0.f;
    for (int i = 0; i < 128; ++i) {
        float xv = xs[lane][i];
        const float* wr = wt + i * 128 + og;
#pragma unroll
        for (int o = 0; o < 32; o++) acc[o] = fmaf(xv, wr[o], acc[o]);
    }
#pragma unroll
    for (int o = 0; o < 32; o++) {
        int oc = og + o;
        size_t oidx = (size_t)(b * 128 + oc) * NSP + n0 + lane;
        float v = acc[o] + bias[oc];
        if (add) v += add[oidx];
        out[oidx] = v;
    }
}

// ---------- depthwise 3x3 reflect-pad + bias + LeakyReLU, out += result ----------
__global__ __launch_bounds__(256) void dw_kernel(const float* __restrict__ h2,
                                                 const float* __restrict__ dww,
                                                 const float* __restrict__ dwb,
                                                 float* __restrict__ out) {
    size_t idx = (size_t)blockIdx.x * 256 + threadIdx.x;   // B*C*N = 16777216 exact
    int w = (int)(idx & 127);
    int hh = (int)((idx >> 7) & 127);
    int bc = (int)(idx >> 14);
    int c = bc & 127;
    const float* src = h2 + ((size_t)bc << 14);
    float s = dwb[c];
#pragma unroll
    for (int kh = 0; kh < 3; kh++) {
        int ih = hh + kh - 1;
        ih = ih < 0 ? 1 : (ih > 127 ? 126 : ih);
#pragma unroll
        for (int kw = 0; kw < 3; kw++) {
            int iw = w + kw - 1;
            iw = iw < 0 ? 1 : (iw > 127 ? 126 : iw);
            s = fmaf(src[ih * 128 + iw], dww[c * 9 + kh * 3 + kw], s);
        }
    }
    s = s >= 0.f ? s : SLOPE * s;
    out[idx] += s;
}

extern "C" void kernel_launch(void* const* d_in, const int* in_sizes, int n_in,
                              void* d_out, int out_size, void* d_ws, size_t ws_size,
                              hipStream_t stream) {
    const float* x1   = (const float*)d_in[0];
    const float* x2   = (const float*)d_in[1];
    const float* temp = (const float*)d_in[2];
    const float* c1w  = (const float*)d_in[3];
    const float* c1b  = (const float*)d_in[4];
    const float* c2w  = (const float*)d_in[5];
    const float* c2b  = (const float*)d_in[6];
    const float* dww  = (const float*)d_in[7];
    const float* dwb  = (const float*)d_in[8];
    const float* scw  = (const float*)d_in[9];
    const float* scb  = (const float*)d_in[10];
    float* out = (float*)d_out;
    char* ws = (char*)d_ws;

    float*          G    = (float*)(ws);                       // 32 KB
    float*          attn = (float*)(ws + (32 << 10));          // 32 KB
    __hip_bfloat16* wb1  = (__hip_bfloat16*)(ws + (64 << 10)); // 288 KB
    float*          wt2  = (float*)(ws + (384 << 10));         // 64 KB
    float*          wtsc = (float*)(ws + (448 << 10));         // 64 KB
    __hip_bfloat16* yt   = (__hip_bfloat16*)(ws + ((size_t)1 << 20));  // 32 MiB (NHWC bf16)
    float*          h2   = (float*)(ws + ((size_t)1 << 20));           // 64 MiB (reuses yt region later)
    float*          h1   = (float*)(ws + ((size_t)65 << 20));          // 64 MiB

    prep_wb1<<<576, 256, 0, stream>>>(c1w, wb1);
    transpose_1x1_w<<<64, 256, 0, stream>>>(c2w, wt2);
    transpose_1x1_w<<<64, 256, 0, stream>>>(scw, wtsc);

    gram_kernel<<<128, 256, 0, stream>>>(x1, G);
    softmax_kernel<<<128, 64, 0, stream>>>(G, temp, attn);
    av_kernel<<<dim3(64, 128), 256, 0, stream>>>(x2, attn, yt);

    conv1_mfma<<<1024, 256, 0, stream>>>(yt, wb1, c1b, h1);           // h1 = leaky(conv3x3(y))
    conv1x1_bf<<<2048, 256, 0, stream>>>(yt, wtsc, scb, x1, out);     // out = sc(y) + x1 (yt dead after)
    conv1x1_kernel<<<2048, 256, 0, stream>>>(h1, wt2, c2b, nullptr, h2); // h2 = conv2(h1)
    dw_kernel<<<65536, 256, 0, stream>>>(h2, dww, dwb, out);          // out += leaky(dw(h2))
}

// Round 3
// 227.803 us; speedup vs baseline: 3.2731x; 1.6880x over previous
//
#include <hip/hip_runtime.h>
#include <hip/hip_bf16.h>

typedef __attribute__((ext_vector_type(8))) short short8;
typedef __attribute__((ext_vector_type(4))) float f32x4;

#define NB 8
#define NC 128
#define NHW 128
#define NSP (NHW*NHW)     // 16384
#define SLOPE 0.2f
#define EPSN 1e-12f

static __device__ __forceinline__ unsigned short f2bf(float f) {
    __hip_bfloat16 h = __float2bfloat16(f);
    return *reinterpret_cast<unsigned short*>(&h);
}
static __device__ __forceinline__ float bf2f(__hip_bfloat16 h) {
    return __bfloat162float(h);
}

// ---------- weight prep ----------
// conv1_w [o][i][kh][kw] fp32 -> wb1 [tap][o][i] bf16
__global__ void prep_wb1(const float* __restrict__ w, __hip_bfloat16* __restrict__ wb) {
    int idx = blockIdx.x * 256 + threadIdx.x;          // 147456
    if (idx >= 128 * 128 * 9) return;
    int kw = idx % 3; int t = idx / 3;
    int kh = t % 3;   t /= 3;
    int i  = t % 128; int o = t / 128;
    wb[((size_t)(kh * 3 + kw) * 128 + o) * 128 + i] = __float2bfloat16(w[idx]);
}

// 1x1 w [o][i] fp32 -> bf16 same layout
__global__ void prep_w1x1(const float* __restrict__ w, __hip_bfloat16* __restrict__ wb) {
    int idx = blockIdx.x * 256 + threadIdx.x;          // 16384
    if (idx >= 128 * 128) return;
    wb[idx] = __float2bfloat16(w[idx]);
}

// ---------- gram: partial over spatial quarter ----------
__global__ __launch_bounds__(256) void gram_part(const float* __restrict__ x1,
                                                 float* __restrict__ Gp) {
    int bh = blockIdx.x & 127;
    int q  = blockIdx.x >> 7;                           // 0..3
    const float* base = x1 + (size_t)bh * 8 * NSP + q * 4096;
    float acc[8][8];
#pragma unroll
    for (int c = 0; c < 8; c++)
#pragma unroll
        for (int d = 0; d < 8; d++) acc[c][d] = 0.f;

    for (int n = threadIdx.x; n < 4096; n += 256) {
        float v[8];
#pragma unroll
        for (int c = 0; c < 8; c++) v[c] = base[c * NSP + n];
#pragma unroll
        for (int c = 0; c < 8; c++)
#pragma unroll
            for (int d = 0; d < 8; d++)
                acc[c][d] = fmaf(v[c], v[d], acc[c][d]);
    }
#pragma unroll
    for (int c = 0; c < 8; c++)
#pragma unroll
        for (int d = 0; d < 8; d++)
            for (int off = 32; off > 0; off >>= 1)
                acc[c][d] += __shfl_down(acc[c][d], off);

    __shared__ float red[4][64];
    int wv = threadIdx.x >> 6;
    if ((threadIdx.x & 63) == 0) {
#pragma unroll
        for (int c = 0; c < 8; c++)
#pragma unroll
            for (int d = 0; d < 8; d++) red[wv][c * 8 + d] = acc[c][d];
    }
    __syncthreads();
    if (threadIdx.x < 64)
        Gp[(size_t)(q * 128 + bh) * 64 + threadIdx.x] =
            red[0][threadIdx.x] + red[1][threadIdx.x] + red[2][threadIdx.x] + red[3][threadIdx.x];
}

__global__ void gram_reduce(const float* __restrict__ Gp, float* __restrict__ G) {
    int bh = blockIdx.x;
    int t = threadIdx.x;
    float s = 0.f;
#pragma unroll
    for (int q = 0; q < 4; q++) s += Gp[(size_t)(q * 128 + bh) * 64 + t];
    G[bh * 64 + t] = s;
}

// ---------- softmax over 8x8 logits ----------
__global__ void softmax_kernel(const float* __restrict__ G, const float* __restrict__ temp,
                               float* __restrict__ attn) {
    int bh = blockIdx.x; int h = bh & 15;
    int t = threadIdx.x;
    int c = t >> 3, d = t & 7;
    const float* g = G + bh * 64;
    float nc = fmaxf(sqrtf(g[c * 8 + c]), EPSN);
    float nd = fmaxf(sqrtf(g[d * 8 + d]), EPSN);
    float a = g[t] / (nc * nd) * temp[h];
    float m = a;
#pragma unroll
    for (int off = 4; off > 0; off >>= 1) m = fmaxf(m, __shfl_xor(m, off));
    float e = __expf(a - m);
    float s = e;
#pragma unroll
    for (int off = 4; off > 0; off >>= 1) s += __shfl_xor(s, off);
    attn[bh * 64 + t] = e / s;
}

// ---------- av: y_t = attn @ v, NHWC bf16, coalesced writes ----------
__global__ __launch_bounds__(256) void av_v2(const float* __restrict__ x2,
                                             const float* __restrict__ attn,
                                             __hip_bfloat16* __restrict__ yt) {
    int b  = blockIdx.x >> 8;
    int p0 = (blockIdx.x & 255) << 6;       // 64 positions
    __shared__ float vt[128][65];
    __shared__ float at[16][65];
    for (int idx = threadIdx.x; idx < 1024; idx += 256)
        at[idx >> 6][idx & 63] = attn[(size_t)b * 1024 + idx];
    for (int idx = threadIdx.x; idx < 8192; idx += 256) {
        int row = idx >> 6, col = idx & 63;
        vt[row][col] = x2[(size_t)(b * 128 + row) * NSP + p0 + col];
    }
    __syncthreads();
    for (int idx = threadIdx.x; idx < 1024; idx += 256) {
        int cq = idx & 15;                  // head
        int p  = idx >> 4;                  // 0..63
        float vv[8];
#pragma unroll
        for (int d = 0; d < 8; d++) vv[d] = vt[cq * 8 + d][p];
        unsigned int pk[4];
#pragma unroll
        for (int c = 0; c < 8; c += 2) {
            float s0 = 0.f, s1 = 0.f;
#pragma unroll
            for (int d = 0; d < 8; d++) {
                s0 = fmaf(at[cq][c * 8 + d], vv[d], s0);
                s1 = fmaf(at[cq][(c + 1) * 8 + d], vv[d], s1);
            }
            pk[c >> 1] = (unsigned int)f2bf(s0) | ((unsigned int)f2bf(s1) << 16);
        }
        uint4 st; st.x = pk[0]; st.y = pk[1]; st.z = pk[2]; st.w = pk[3];
        *reinterpret_cast<uint4*>(yt + ((size_t)b * NSP + p0 + p) * 128 + cq * 8) = st;
    }
}

// ---------- fused conv block: conv1(3x3,leaky) -> conv2(1x1)->h2 ; sc(1x1)+x1 -> out ----------
// Block = (b, row h). M=128 (w), N=128. 4 waves, grid 2m x 2n, each 4x4 16x16 frags.
__global__ __launch_bounds__(256, 3) void fused_conv(const __hip_bfloat16* __restrict__ yt,
                                                     const __hip_bfloat16* __restrict__ wb1,
                                                     const __hip_bfloat16* __restrict__ wb2,
                                                     const __hip_bfloat16* __restrict__ wbsc,
                                                     const float* __restrict__ b1,
                                                     const float* __restrict__ b2,
                                                     const float* __restrict__ bsc,
                                                     const float* __restrict__ x1,
                                                     __hip_bfloat16* __restrict__ h2,
                                                     float* __restrict__ out) {
    __shared__ uint4 smem[3168];          // conv1 stage: [r:3][col:132][g:8]; reused as bf16 tile [128][128] swizzled
    char* smem_raw = (char*)smem;
    int blk = blockIdx.x;
    int b = blk >> 7, h = blk & 127;
    int tid = threadIdx.x;
    int lane = tid & 63;
    int wid = tid >> 6;
    int wm = wid >> 1, wn = wid & 1;
    int l15 = lane & 15;
    int lk = lane >> 4;

    f32x4 acc[4][4];
#pragma unroll
    for (int a = 0; a < 4; a++)
#pragma unroll
        for (int c = 0; c < 4; c++) acc[a][c] = (f32x4){0.f, 0.f, 0.f, 0.f};

    // ---- conv1 ----
#pragma unroll
    for (int half = 0; half < 2; ++half) {
        __syncthreads();
        for (int idx = tid; idx < 3168; idx += 256) {
            int chunk = idx & 7;
            int colr = idx >> 3;
            int col = colr % 132;
            int r = colr / 132;
            int hh = h + r - 1;
            int w = col - 1;
            uint4 v = make_uint4(0u, 0u, 0u, 0u);
            if ((unsigned)hh < 128u && (unsigned)w < 128u)
                v = *reinterpret_cast<const uint4*>(
                    yt + (((size_t)(b * 128 + hh)) * 128 + w) * 128 + half * 64 + chunk * 8);
            smem[r * 1056 + col * 8 + (chunk ^ (col & 7))] = v;
        }
        __syncthreads();

#pragma unroll
        for (int t = 0; t < 9; ++t) {
            int kh = t / 3, kw = t % 3;
            const __hip_bfloat16* wrow = wb1 + ((size_t)t * 128 + wn * 64 + l15) * 128 + half * 64 + lk * 8;
#pragma unroll
            for (int icc = 0; icc < 2; ++icc) {
                short8 bfr[4];
#pragma unroll
                for (int c = 0; c < 4; ++c)
                    bfr[c] = *reinterpret_cast<const short8*>(wrow + c * 2048 + icc * 32);
                short8 afr[4];
#pragma unroll
                for (int a = 0; a < 4; ++a) {
                    int col = (wm * 4 + a) * 16 + l15 + kw;
                    int chunk = icc * 4 + lk;
                    afr[a] = *reinterpret_cast<const short8*>(
                        &smem[kh * 1056 + col * 8 + (chunk ^ (col & 7))]);
                }
#pragma unroll
                for (int a = 0; a < 4; ++a)
#pragma unroll
                    for (int c = 0; c < 4; ++c)
                        acc[a][c] = __builtin_amdgcn_mfma_f32_16x16x32_bf16(
                            afr[a], bfr[c], acc[a][c], 0, 0, 0);
            }
        }
    }

    // ---- h1 = bias+leaky -> LDS bf16 tile [p][o], granule-XOR swizzled ----
    __syncthreads();   // all waves done reading conv1 stage
#pragma unroll
    for (int c = 0; c < 4; ++c) {
        int o = wn * 64 + c * 16 + l15;
        float bv = b1[o];
        int go = o >> 3, ob = (o & 7) << 1;
#pragma unroll
        for (int a = 0; a < 4; ++a) {
            int pb = (wm * 4 + a) * 16 + lk * 4;
#pragma unroll
            for (int j = 0; j < 4; ++j) {
                int p = pb + j;
                float v = acc[a][c][j] + bv;
                v = v >= 0.f ? v : SLOPE * v;
                *reinterpret_cast<__hip_bfloat16*>(
                    smem_raw + p * 256 + (((go ^ (p & 15)) << 4) | ob)) = __float2bfloat16(v);
            }
        }
    }
    __syncthreads();

    // ---- conv2: h2 = W2 @ h1 + b2  (bf16 NCHW out) ----
#pragma unroll
    for (int a = 0; a < 4; a++)
#pragma unroll
        for (int c = 0; c < 4; c++) acc[a][c] = (f32x4){0.f, 0.f, 0.f, 0.f};
#pragma unroll
    for (int kk = 0; kk < 4; ++kk) {
        short8 bfr[4];
#pragma unroll
        for (int c = 0; c < 4; ++c)
            bfr[c] = *reinterpret_cast<const short8*>(
                wb2 + (size_t)(wn * 64 + c * 16 + l15) * 128 + kk * 32 + lk * 8);
        short8 afr[4];
        int g = kk * 4 + lk;
#pragma unroll
        for (int a = 0; a < 4; ++a) {
            int p = (wm * 4 + a) * 16 + l15;
            afr[a] = *reinterpret_cast<const short8*>(smem_raw + p * 256 + ((g ^ (p & 15)) << 4));
        }
#pragma unroll
        for (int a = 0; a < 4; ++a)
#pragma unroll
            for (int c = 0; c < 4; ++c)
                acc[a][c] = __builtin_amdgcn_mfma_f32_16x16x32_bf16(afr[a], bfr[c], acc[a][c], 0, 0, 0);
    }
#pragma unroll
    for (int c = 0; c < 4; ++c) {
        int o = wn * 64 + c * 16 + l15;
        float bv = b2[o];
        size_t obase = ((size_t)(b * 128 + o) * 128 + h) * 128;
#pragma unroll
        for (int a = 0; a < 4; ++a) {
            int w0 = (wm * 4 + a) * 16 + lk * 4;
            uint2 st;
            st.x = (unsigned int)f2bf(acc[a][c][0] + bv) | ((unsigned int)f2bf(acc[a][c][1] + bv) << 16);
            st.y = (unsigned int)f2bf(acc[a][c][2] + bv) | ((unsigned int)f2bf(acc[a][c][3] + bv) << 16);
            *reinterpret_cast<uint2*>(h2 + obase + w0) = st;
        }
    }

    // ---- stage y row h into tile, then sc + x1 -> out ----
    __syncthreads();   // conv2 tile reads done
    for (int idx = tid; idx < 2048; idx += 256) {
        int p = idx >> 4, g = idx & 15;
        uint4 v = *reinterpret_cast<const uint4*>(
            yt + ((size_t)(b * NSP + h * 128 + p)) * 128 + g * 8);
        *reinterpret_cast<uint4*>(smem_raw + p * 256 + ((g ^ (p & 15)) << 4)) = v;
    }
    __syncthreads();

#pragma unroll
    for (int a = 0; a < 4; a++)
#pragma unroll
        for (int c = 0; c < 4; c++) acc[a][c] = (f32x4){0.f, 0.f, 0.f, 0.f};
#pragma unroll
    for (int kk = 0; kk < 4; ++kk) {
        short8 bfr[4];
#pragma unroll
        for (int c = 0; c < 4; ++c)
            bfr[c] = *reinterpret_cast<const short8*>(
                wbsc + (size_t)(wn * 64 + c * 16 + l15) * 128 + kk * 32 + lk * 8);
        short8 afr[4];
        int g = kk * 4 + lk;
#pragma unroll
        for (int a = 0; a < 4; ++a) {
            int p = (wm * 4 + a) * 16 + l15;
            afr[a] = *reinterpret_cast<const short8*>(smem_raw + p * 256 + ((g ^ (p & 15)) << 4));
        }
#pragma unroll
        for (int a = 0; a < 4; ++a)
#pragma unroll
            for (int c = 0; c < 4; ++c)
                acc[a][c] = __builtin_amdgcn_mfma_f32_16x16x32_bf16(afr[a], bfr[c], acc[a][c], 0, 0, 0);
    }
#pragma unroll
    for (int c = 0; c < 4; ++c) {
        int o = wn * 64 + c * 16 + l15;
        float bv = bsc[o];
        size_t obase = ((size_t)(b * 128 + o) * 128 + h) * 128;
#pragma unroll
        for (int a = 0; a < 4; ++a) {
            int w0 = (wm * 4 + a) * 16 + lk * 4;
            float4 xv = *reinterpret_cast<const float4*>(x1 + obase + w0);
            float4 st;
            st.x = acc[a][c][0] + bv + xv.x;
            st.y = acc[a][c][1] + bv + xv.y;
            st.z = acc[a][c][2] + bv + xv.z;
            st.w = acc[a][c][3] + bv + xv.w;
            *reinterpret_cast<float4*>(out + obase + w0) = st;
        }
    }
}

// ---------- depthwise 3x3 reflect-pad + bias + LeakyReLU, out += result (bf16 h2) ----------
__global__ __launch_bounds__(256) void dw_kernel(const __hip_bfloat16* __restrict__ h2,
                                                 const float* __restrict__ dww,
                                                 const float* __restrict__ dwb,
                                                 float* __restrict__ out) {
    size_t idx = (size_t)blockIdx.x * 256 + threadIdx.x;   // 16777216
    int w = (int)(idx & 127);
    int hh = (int)((idx >> 7) & 127);
    int bc = (int)(idx >> 14);
    int c = bc & 127;
    const __hip_bfloat16* src = h2 + ((size_t)bc << 14);
    float s = dwb[c];
#pragma unroll
    for (int kh = 0; kh < 3; kh++) {
        int ih = hh + kh - 1;
        ih = ih < 0 ? 1 : (ih > 127 ? 126 : ih);
#pragma unroll
        for (int kw = 0; kw < 3; kw++) {
            int iw = w + kw - 1;
            iw = iw < 0 ? 1 : (iw > 127 ? 126 : iw);
            s = fmaf(bf2f(src[ih * 128 + iw]), dww[c * 9 + kh * 3 + kw], s);
        }
    }
    s = s >= 0.f ? s : SLOPE * s;
    out[idx] += s;
}

extern "C" void kernel_launch(void* const* d_in, const int* in_sizes, int n_in,
                              void* d_out, int out_size, void* d_ws, size_t ws_size,
                              hipStream_t stream) {
    const float* x1   = (const float*)d_in[0];
    const float* x2   = (const float*)d_in[1];
    const float* temp = (const float*)d_in[2];
    const float* c1w  = (const float*)d_in[3];
    const float* c1b  = (const float*)d_in[4];
    const float* c2w  = (const float*)d_in[5];
    const float* c2b  = (const float*)d_in[6];
    const float* dww  = (const float*)d_in[7];
    const float* dwb  = (const float*)d_in[8];
    const float* scw  = (const float*)d_in[9];
    const float* scb  = (const float*)d_in[10];
    float* out = (float*)d_out;
    char* ws = (char*)d_ws;

    float*          G    = (float*)(ws);                        // 32 KB
    float*          attn = (float*)(ws + (32 << 10));           // 32 KB
    float*          Gp   = (float*)(ws + (64 << 10));           // 128 KB
    __hip_bfloat16* wb1  = (__hip_bfloat16*)(ws + (192 << 10)); // 288 KB
    __hip_bfloat16* wb2  = (__hip_bfloat16*)(ws + (480 << 10)); // 32 KB
    __hip_bfloat16* wbsc = (__hip_bfloat16*)(ws + (512 << 10)); // 32 KB
    __hip_bfloat16* yt   = (__hip_bfloat16*)(ws + ((size_t)1 << 20));   // 32 MiB NHWC bf16
    __hip_bfloat16* h2b  = (__hip_bfloat16*)(ws + ((size_t)34 << 20));  // 32 MiB NCHW bf16

    prep_wb1<<<576, 256, 0, stream>>>(c1w, wb1);
    prep_w1x1<<<64, 256, 0, stream>>>(c2w, wb2);
    prep_w1x1<<<64, 256, 0, stream>>>(scw, wbsc);

    gram_part<<<512, 256, 0, stream>>>(x1, Gp);
    gram_reduce<<<128, 64, 0, stream>>>(Gp, G);
    softmax_kernel<<<128, 64, 0, stream>>>(G, temp, attn);
    av_v2<<<2048, 256, 0, stream>>>(x2, attn, yt);

    fused_conv<<<1024, 256, 0, stream>>>(yt, wb1, wb2, wbsc, c1b, c2b, scb, x1, h2b, out);
    dw_kernel<<<65536, 256, 0, stream>>>(h2b, dww, dwb, out);
}

// Round 4
// 227.231 us; speedup vs baseline: 3.2814x; 1.0025x over previous
//
#include <hip/hip_runtime.h>
#include <hip/hip_bf16.h>

typedef __attribute__((ext_vector_type(8))) short short8;
typedef __attribute__((ext_vector_type(4))) float f32x4;

#define NB 8
#define NC 128
#define NHW 128
#define NSP (NHW*NHW)     // 16384
#define SLOPE 0.2f
#define EPSN 1e-12f

static __device__ __forceinline__ unsigned short f2bf(float f) {
    __hip_bfloat16 h = __float2bfloat16(f);
    return *reinterpret_cast<unsigned short*>(&h);
}
static __device__ __forceinline__ float bf2f(__hip_bfloat16 h) {
    return __bfloat162float(h);
}

// ---------- weight prep ----------
// conv1_w [o][i][kh][kw] fp32 -> wb1 [tap][o][i] bf16
__global__ void prep_wb1(const float* __restrict__ w, __hip_bfloat16* __restrict__ wb) {
    int idx = blockIdx.x * 256 + threadIdx.x;          // 147456
    if (idx >= 128 * 128 * 9) return;
    int kw = idx % 3; int t = idx / 3;
    int kh = t % 3;   t /= 3;
    int i  = t % 128; int o = t / 128;
    wb[((size_t)(kh * 3 + kw) * 128 + o) * 128 + i] = __float2bfloat16(w[idx]);
}

// 1x1 w [o][i] fp32 -> bf16 same layout
__global__ void prep_w1x1(const float* __restrict__ w, __hip_bfloat16* __restrict__ wb) {
    int idx = blockIdx.x * 256 + threadIdx.x;          // 16384
    if (idx >= 128 * 128) return;
    wb[idx] = __float2bfloat16(w[idx]);
}

// ---------- gram: partial over spatial quarter ----------
__global__ __launch_bounds__(256) void gram_part(const float* __restrict__ x1,
                                                 float* __restrict__ Gp) {
    int bh = blockIdx.x & 127;
    int q  = blockIdx.x >> 7;                           // 0..3
    const float* base = x1 + (size_t)bh * 8 * NSP + q * 4096;
    float acc[8][8];
#pragma unroll
    for (int c = 0; c < 8; c++)
#pragma unroll
        for (int d = 0; d < 8; d++) acc[c][d] = 0.f;

    for (int n = threadIdx.x; n < 4096; n += 256) {
        float v[8];
#pragma unroll
        for (int c = 0; c < 8; c++) v[c] = base[c * NSP + n];
#pragma unroll
        for (int c = 0; c < 8; c++)
#pragma unroll
            for (int d = 0; d < 8; d++)
                acc[c][d] = fmaf(v[c], v[d], acc[c][d]);
    }
#pragma unroll
    for (int c = 0; c < 8; c++)
#pragma unroll
        for (int d = 0; d < 8; d++)
            for (int off = 32; off > 0; off >>= 1)
                acc[c][d] += __shfl_down(acc[c][d], off);

    __shared__ float red[4][64];
    int wv = threadIdx.x >> 6;
    if ((threadIdx.x & 63) == 0) {
#pragma unroll
        for (int c = 0; c < 8; c++)
#pragma unroll
            for (int d = 0; d < 8; d++) red[wv][c * 8 + d] = acc[c][d];
    }
    __syncthreads();
    if (threadIdx.x < 64)
        Gp[(size_t)(q * 128 + bh) * 64 + threadIdx.x] =
            red[0][threadIdx.x] + red[1][threadIdx.x] + red[2][threadIdx.x] + red[3][threadIdx.x];
}

__global__ void gram_reduce(const float* __restrict__ Gp, float* __restrict__ G) {
    int bh = blockIdx.x;
    int t = threadIdx.x;
    float s = 0.f;
#pragma unroll
    for (int q = 0; q < 4; q++) s += Gp[(size_t)(q * 128 + bh) * 64 + t];
    G[bh * 64 + t] = s;
}

// ---------- softmax over 8x8 logits ----------
__global__ void softmax_kernel(const float* __restrict__ G, const float* __restrict__ temp,
                               float* __restrict__ attn) {
    int bh = blockIdx.x; int h = bh & 15;
    int t = threadIdx.x;
    int c = t >> 3, d = t & 7;
    const float* g = G + bh * 64;
    float nc = fmaxf(sqrtf(g[c * 8 + c]), EPSN);
    float nd = fmaxf(sqrtf(g[d * 8 + d]), EPSN);
    float a = g[t] / (nc * nd) * temp[h];
    float m = a;
#pragma unroll
    for (int off = 4; off > 0; off >>= 1) m = fmaxf(m, __shfl_xor(m, off));
    float e = __expf(a - m);
    float s = e;
#pragma unroll
    for (int off = 4; off > 0; off >>= 1) s += __shfl_xor(s, off);
    attn[bh * 64 + t] = e / s;
}

// ---------- av: y_t = attn @ v, NHWC bf16, coalesced writes ----------
__global__ __launch_bounds__(256) void av_v2(const float* __restrict__ x2,
                                             const float* __restrict__ attn,
                                             __hip_bfloat16* __restrict__ yt) {
    int b  = blockIdx.x >> 8;
    int p0 = (blockIdx.x & 255) << 6;       // 64 positions
    __shared__ float vt[128][65];
    __shared__ float at[16][65];
    for (int idx = threadIdx.x; idx < 1024; idx += 256)
        at[idx >> 6][idx & 63] = attn[(size_t)b * 1024 + idx];
    for (int idx = threadIdx.x; idx < 8192; idx += 256) {
        int row = idx >> 6, col = idx & 63;
        vt[row][col] = x2[(size_t)(b * 128 + row) * NSP + p0 + col];
    }
    __syncthreads();
    for (int idx = threadIdx.x; idx < 1024; idx += 256) {
        int cq = idx & 15;                  // head
        int p  = idx >> 4;                  // 0..63
        float vv[8];
#pragma unroll
        for (int d = 0; d < 8; d++) vv[d] = vt[cq * 8 + d][p];
        unsigned int pk[4];
#pragma unroll
        for (int c = 0; c < 8; c += 2) {
            float s0 = 0.f, s1 = 0.f;
#pragma unroll
            for (int d = 0; d < 8; d++) {
                s0 = fmaf(at[cq][c * 8 + d], vv[d], s0);
                s1 = fmaf(at[cq][(c + 1) * 8 + d], vv[d], s1);
            }
            pk[c >> 1] = (unsigned int)f2bf(s0) | ((unsigned int)f2bf(s1) << 16);
        }
        uint4 st; st.x = pk[0]; st.y = pk[1]; st.z = pk[2]; st.w = pk[3];
        *reinterpret_cast<uint4*>(yt + ((size_t)b * NSP + p0 + p) * 128 + cq * 8) = st;
    }
}

// ---------- fused conv block: conv1(3x3,leaky) -> conv2(1x1)->h2 ; sc(1x1)+x1 -> out ----------
// Block = (b, row h), XCD-chunk-swizzled. M=128 (w), N=128. 4 waves, 2m x 2n, 4x4 frags each.
// conv1 K-loop: depth-1 register-prefetched (weights from global/L2, A-frags from LDS).
__global__ __launch_bounds__(256, 3) void fused_conv(const __hip_bfloat16* __restrict__ yt,
                                                     const __hip_bfloat16* __restrict__ wb1,
                                                     const __hip_bfloat16* __restrict__ wb2,
                                                     const __hip_bfloat16* __restrict__ wbsc,
                                                     const float* __restrict__ b1,
                                                     const float* __restrict__ b2,
                                                     const float* __restrict__ bsc,
                                                     const float* __restrict__ x1,
                                                     __hip_bfloat16* __restrict__ h2,
                                                     float* __restrict__ out) {
    __shared__ uint4 smem[3168];          // conv1 stage: [r:3][col:132][g:8]; reused as bf16 tile [128][128] swizzled
    char* smem_raw = (char*)smem;
    int bid = blockIdx.x;
    int blk = (bid & 7) * 128 + (bid >> 3);   // XCD-chunked: each XCD owns one batch image
    int b = blk >> 7, h = blk & 127;
    int tid = threadIdx.x;
    int lane = tid & 63;
    int wid = tid >> 6;
    int wm = wid >> 1, wn = wid & 1;
    int l15 = lane & 15;
    int lk = lane >> 4;

    f32x4 acc[4][4];
#pragma unroll
    for (int a = 0; a < 4; a++)
#pragma unroll
        for (int c = 0; c < 4; c++) acc[a][c] = (f32x4){0.f, 0.f, 0.f, 0.f};

    // ---- conv1 with depth-1 software pipeline ----
#pragma unroll
    for (int half = 0; half < 2; ++half) {
        __syncthreads();
        for (int idx = tid; idx < 3168; idx += 256) {
            int chunk = idx & 7;
            int colr = idx >> 3;
            int col = colr % 132;
            int r = colr / 132;
            int hh = h + r - 1;
            int w = col - 1;
            uint4 v = make_uint4(0u, 0u, 0u, 0u);
            if ((unsigned)hh < 128u && (unsigned)w < 128u)
                v = *reinterpret_cast<const uint4*>(
                    yt + (((size_t)(b * 128 + hh)) * 128 + w) * 128 + half * 64 + chunk * 8);
            smem[r * 1056 + col * 8 + (chunk ^ (col & 7))] = v;
        }
        __syncthreads();

        const __hip_bfloat16* wbase = wb1 + (size_t)(wn * 64 + l15) * 128 + half * 64 + lk * 8;

        auto loadB = [&](int gi2, short8 (&dst)[4]) {
            const __hip_bfloat16* w = wbase + (gi2 >> 1) * 16384 + (gi2 & 1) * 32;
#pragma unroll
            for (int cc = 0; cc < 4; ++cc)
                dst[cc] = *reinterpret_cast<const short8*>(w + cc * 2048);
        };
        auto loadA = [&](int gi2, short8 (&dst)[4]) {
            int t = gi2 >> 1;
            int kh = t / 3, kw = t - kh * 3;
            int g = (gi2 & 1) * 4 + lk;
#pragma unroll
            for (int a = 0; a < 4; ++a) {
                int col = (wm * 4 + a) * 16 + l15 + kw;
                dst[a] = *reinterpret_cast<const short8*>(
                    &smem[kh * 1056 + col * 8 + (g ^ (col & 7))]);
            }
        };

        short8 bq[2][4], aq[2][4];
        loadB(0, bq[0]);
        loadA(0, aq[0]);
#pragma unroll
        for (int gi = 0; gi < 18; ++gi) {
            const int cur = gi & 1, nxt = cur ^ 1;
            if (gi < 17) {
                loadB(gi + 1, bq[nxt]);
                loadA(gi + 1, aq[nxt]);
            }
#pragma unroll
            for (int a = 0; a < 4; ++a)
#pragma unroll
                for (int c = 0; c < 4; ++c)
                    acc[a][c] = __builtin_amdgcn_mfma_f32_16x16x32_bf16(
                        aq[cur][a], bq[cur][c], acc[a][c], 0, 0, 0);
        }
    }

    // ---- h1 = bias+leaky -> LDS bf16 tile [p][o], granule-XOR swizzled ----
    __syncthreads();   // all waves done reading conv1 stage
#pragma unroll
    for (int c = 0; c < 4; ++c) {
        int o = wn * 64 + c * 16 + l15;
        float bv = b1[o];
        int go = o >> 3, ob = (o & 7) << 1;
#pragma unroll
        for (int a = 0; a < 4; ++a) {
            int pb = (wm * 4 + a) * 16 + lk * 4;
#pragma unroll
            for (int j = 0; j < 4; ++j) {
                int p = pb + j;
                float v = acc[a][c][j] + bv;
                v = v >= 0.f ? v : SLOPE * v;
                *reinterpret_cast<__hip_bfloat16*>(
                    smem_raw + p * 256 + (((go ^ (p & 15)) << 4) | ob)) = __float2bfloat16(v);
            }
        }
    }
    __syncthreads();

    // ---- conv2: h2 = W2 @ h1 + b2  (bf16 NCHW out) ----
#pragma unroll
    for (int a = 0; a < 4; a++)
#pragma unroll
        for (int c = 0; c < 4; c++) acc[a][c] = (f32x4){0.f, 0.f, 0.f, 0.f};
#pragma unroll
    for (int kk = 0; kk < 4; ++kk) {
        short8 bfr[4];
#pragma unroll
        for (int c = 0; c < 4; ++c)
            bfr[c] = *reinterpret_cast<const short8*>(
                wb2 + (size_t)(wn * 64 + c * 16 + l15) * 128 + kk * 32 + lk * 8);
        short8 afr[4];
        int g = kk * 4 + lk;
#pragma unroll
        for (int a = 0; a < 4; ++a) {
            int p = (wm * 4 + a) * 16 + l15;
            afr[a] = *reinterpret_cast<const short8*>(smem_raw + p * 256 + ((g ^ (p & 15)) << 4));
        }
#pragma unroll
        for (int a = 0; a < 4; ++a)
#pragma unroll
            for (int c = 0; c < 4; ++c)
                acc[a][c] = __builtin_amdgcn_mfma_f32_16x16x32_bf16(afr[a], bfr[c], acc[a][c], 0, 0, 0);
    }
#pragma unroll
    for (int c = 0; c < 4; ++c) {
        int o = wn * 64 + c * 16 + l15;
        float bv = b2[o];
        size_t obase = ((size_t)(b * 128 + o) * 128 + h) * 128;
#pragma unroll
        for (int a = 0; a < 4; ++a) {
            int w0 = (wm * 4 + a) * 16 + lk * 4;
            uint2 st;
            st.x = (unsigned int)f2bf(acc[a][c][0] + bv) | ((unsigned int)f2bf(acc[a][c][1] + bv) << 16);
            st.y = (unsigned int)f2bf(acc[a][c][2] + bv) | ((unsigned int)f2bf(acc[a][c][3] + bv) << 16);
            *reinterpret_cast<uint2*>(h2 + obase + w0) = st;
        }
    }

    // ---- stage y row h into tile, then sc + x1 -> out ----
    __syncthreads();   // conv2 tile reads done
    for (int idx = tid; idx < 2048; idx += 256) {
        int p = idx >> 4, g = idx & 15;
        uint4 v = *reinterpret_cast<const uint4*>(
            yt + ((size_t)(b * NSP + h * 128 + p)) * 128 + g * 8);
        *reinterpret_cast<uint4*>(smem_raw + p * 256 + ((g ^ (p & 15)) << 4)) = v;
    }
    __syncthreads();

#pragma unroll
    for (int a = 0; a < 4; a++)
#pragma unroll
        for (int c = 0; c < 4; c++) acc[a][c] = (f32x4){0.f, 0.f, 0.f, 0.f};
#pragma unroll
    for (int kk = 0; kk < 4; ++kk) {
        short8 bfr[4];
#pragma unroll
        for (int c = 0; c < 4; ++c)
            bfr[c] = *reinterpret_cast<const short8*>(
                wbsc + (size_t)(wn * 64 + c * 16 + l15) * 128 + kk * 32 + lk * 8);
        short8 afr[4];
        int g = kk * 4 + lk;
#pragma unroll
        for (int a = 0; a < 4; ++a) {
            int p = (wm * 4 + a) * 16 + l15;
            afr[a] = *reinterpret_cast<const short8*>(smem_raw + p * 256 + ((g ^ (p & 15)) << 4));
        }
#pragma unroll
        for (int a = 0; a < 4; ++a)
#pragma unroll
            for (int c = 0; c < 4; ++c)
                acc[a][c] = __builtin_amdgcn_mfma_f32_16x16x32_bf16(afr[a], bfr[c], acc[a][c], 0, 0, 0);
    }
#pragma unroll
    for (int c = 0; c < 4; ++c) {
        int o = wn * 64 + c * 16 + l15;
        float bv = bsc[o];
        size_t obase = ((size_t)(b * 128 + o) * 128 + h) * 128;
#pragma unroll
        for (int a = 0; a < 4; ++a) {
            int w0 = (wm * 4 + a) * 16 + lk * 4;
            float4 xv = *reinterpret_cast<const float4*>(x1 + obase + w0);
            float4 st;
            st.x = acc[a][c][0] + bv + xv.x;
            st.y = acc[a][c][1] + bv + xv.y;
            st.z = acc[a][c][2] + bv + xv.z;
            st.w = acc[a][c][3] + bv + xv.w;
            *reinterpret_cast<float4*>(out + obase + w0) = st;
        }
    }
}

// ---------- depthwise 3x3 reflect-pad + bias + LeakyReLU, out += result (bf16 h2) ----------
// 8 outputs/thread, vectorized row loads, XCD-chunk-swizzled (each XCD one batch image).
__global__ __launch_bounds__(256) void dw_v2(const __hip_bfloat16* __restrict__ h2,
                                             const float* __restrict__ dww,
                                             const float* __restrict__ dwb,
                                             float* __restrict__ out) {
    int bid = blockIdx.x;                          // 8192 blocks
    int swz = (bid & 7) * 1024 + (bid >> 3);
    size_t tidx = (size_t)swz * 256 + threadIdx.x; // 2097152 threads total
    int w0 = (int)((tidx & 15) << 3);
    int hh = (int)((tidx >> 4) & 127);
    int bc = (int)(tidx >> 11);
    int c  = bc & 127;
    const __hip_bfloat16* src = h2 + ((size_t)bc << 14);
    float wg[9];
#pragma unroll
    for (int k = 0; k < 9; ++k) wg[k] = dww[c * 9 + k];
    float bv = dwb[c];
    float a8[8];
#pragma unroll
    for (int j = 0; j < 8; ++j) a8[j] = bv;
#pragma unroll
    for (int kh = 0; kh < 3; ++kh) {
        int ih = hh + kh - 1;
        ih = ih < 0 ? 1 : (ih > 127 ? 126 : ih);
        const __hip_bfloat16* row = src + ih * 128;
        short8 mid = *reinterpret_cast<const short8*>(row + w0);
        float v[10];
        v[0] = bf2f(row[w0 == 0 ? 1 : w0 - 1]);
#pragma unroll
        for (int j = 0; j < 8; ++j)
            v[j + 1] = __uint_as_float((unsigned int)(unsigned short)mid[j] << 16);
        v[9] = bf2f(row[w0 == 120 ? 126 : w0 + 8]);
#pragma unroll
        for (int kw = 0; kw < 3; ++kw)
#pragma unroll
            for (int j = 0; j < 8; ++j)
                a8[j] = fmaf(v[j + kw], wg[kh * 3 + kw], a8[j]);
    }
    size_t ob = ((size_t)bc << 14) + hh * 128 + w0;
    float4 o0 = *reinterpret_cast<const float4*>(out + ob);
    float4 o1 = *reinterpret_cast<const float4*>(out + ob + 4);
#pragma unroll
    for (int j = 0; j < 8; ++j) a8[j] = a8[j] >= 0.f ? a8[j] : SLOPE * a8[j];
    o0.x += a8[0]; o0.y += a8[1]; o0.z += a8[2]; o0.w += a8[3];
    o1.x += a8[4]; o1.y += a8[5]; o1.z += a8[6]; o1.w += a8[7];
    *reinterpret_cast<float4*>(out + ob) = o0;
    *reinterpret_cast<float4*>(out + ob + 4) = o1;
}

extern "C" void kernel_launch(void* const* d_in, const int* in_sizes, int n_in,
                              void* d_out, int out_size, void* d_ws, size_t ws_size,
                              hipStream_t stream) {
    const float* x1   = (const float*)d_in[0];
    const float* x2   = (const float*)d_in[1];
    const float* temp = (const float*)d_in[2];
    const float* c1w  = (const float*)d_in[3];
    const float* c1b  = (const float*)d_in[4];
    const float* c2w  = (const float*)d_in[5];
    const float* c2b  = (const float*)d_in[6];
    const float* dww  = (const float*)d_in[7];
    const float* dwb  = (const float*)d_in[8];
    const float* scw  = (const float*)d_in[9];
    const float* scb  = (const float*)d_in[10];
    float* out = (float*)d_out;
    char* ws = (char*)d_ws;

    float*          G    = (float*)(ws);                        // 32 KB
    float*          attn = (float*)(ws + (32 << 10));           // 32 KB
    float*          Gp   = (float*)(ws + (64 << 10));           // 128 KB
    __hip_bfloat16* wb1  = (__hip_bfloat16*)(ws + (192 << 10)); // 288 KB
    __hip_bfloat16* wb2  = (__hip_bfloat16*)(ws + (480 << 10)); // 32 KB
    __hip_bfloat16* wbsc = (__hip_bfloat16*)(ws + (512 << 10)); // 32 KB
    __hip_bfloat16* yt   = (__hip_bfloat16*)(ws + ((size_t)1 << 20));   // 32 MiB NHWC bf16
    __hip_bfloat16* h2b  = (__hip_bfloat16*)(ws + ((size_t)34 << 20));  // 32 MiB NCHW bf16

    prep_wb1<<<576, 256, 0, stream>>>(c1w, wb1);
    prep_w1x1<<<64, 256, 0, stream>>>(c2w, wb2);
    prep_w1x1<<<64, 256, 0, stream>>>(scw, wbsc);

    gram_part<<<512, 256, 0, stream>>>(x1, Gp);
    gram_reduce<<<128, 64, 0, stream>>>(Gp, G);
    softmax_kernel<<<128, 64, 0, stream>>>(G, temp, attn);
    av_v2<<<2048, 256, 0, stream>>>(x2, attn, yt);

    fused_conv<<<1024, 256, 0, stream>>>(yt, wb1, wb2, wbsc, c1b, c2b, scb, x1, h2b, out);
    dw_v2<<<8192, 256, 0, stream>>>(h2b, dww, dwb, out);
}

// Round 5
// 169.922 us; speedup vs baseline: 4.3881x; 1.3373x over previous
//
#include <hip/hip_runtime.h>
#include <hip/hip_bf16.h>

typedef __attribute__((ext_vector_type(8))) short short8;
typedef __attribute__((ext_vector_type(4))) float f32x4;

#define NB 8
#define NC 128
#define NHW 128
#define NSP (NHW*NHW)     // 16384
#define SLOPE 0.2f
#define EPSN 1e-12f

static __device__ __forceinline__ unsigned short f2bf(float f) {
    __hip_bfloat16 h = __float2bfloat16(f);
    return *reinterpret_cast<unsigned short*>(&h);
}
static __device__ __forceinline__ float bf2f(__hip_bfloat16 h) {
    return __bfloat162float(h);
}

// ---------- weight prep: FRAG-MAJOR layouts ----------
// conv1_w [o][i][3][3] fp32 -> wb1 frag-major bf16:
// chunk = (((tap*2+half)*2+wn)*2+icc)*4+c ; element = chunk*512 + lane*8 + j
// where half=i>>6, icc=(i>>5)&1, lk=(i>>3)&3, j=i&7, wn=o>>6, c=(o>>4)&3, l15=o&15, lane=lk*16+l15
__global__ void prep_wb1(const float* __restrict__ w, __hip_bfloat16* __restrict__ wb) {
    int idx = blockIdx.x * 256 + threadIdx.x;          // 147456
    if (idx >= 128 * 128 * 9) return;
    int kw = idx % 3; int t = idx / 3;
    int kh = t % 3;   t /= 3;
    int i  = t % 128; int o = t / 128;
    int tap = kh * 3 + kw;
    int half = i >> 6, icc = (i >> 5) & 1, lk = (i >> 3) & 3, j = i & 7;
    int wn = o >> 6, c = (o >> 4) & 3, l15 = o & 15;
    int lane = lk * 16 + l15;
    size_t chunk = (((size_t)(tap * 2 + half) * 2 + wn) * 2 + icc) * 4 + c;
    wb[chunk * 512 + lane * 8 + j] = __float2bfloat16(w[idx]);
}

// 1x1 w [o][i] fp32 -> frag-major bf16: chunk = ((wn*4+kk)*4+c), element = chunk*512+lane*8+j
__global__ void prep_w1x1(const float* __restrict__ w, __hip_bfloat16* __restrict__ wb) {
    int idx = blockIdx.x * 256 + threadIdx.x;          // 16384
    if (idx >= 128 * 128) return;
    int i = idx & 127, o = idx >> 7;
    int kk = i >> 5, lk = (i >> 3) & 3, j = i & 7;
    int wn = o >> 6, c = (o >> 4) & 3, l15 = o & 15;
    int lane = lk * 16 + l15;
    size_t chunk = ((size_t)(wn * 4 + kk) * 4 + c);
    wb[chunk * 512 + lane * 8 + j] = __float2bfloat16(w[idx]);
}

// ---------- gram: partial over spatial quarter ----------
__global__ __launch_bounds__(256) void gram_part(const float* __restrict__ x1,
                                                 float* __restrict__ Gp) {
    int bh = blockIdx.x & 127;
    int q  = blockIdx.x >> 7;                           // 0..3
    const float* base = x1 + (size_t)bh * 8 * NSP + q * 4096;
    float acc[8][8];
#pragma unroll
    for (int c = 0; c < 8; c++)
#pragma unroll
        for (int d = 0; d < 8; d++) acc[c][d] = 0.f;

    for (int n = threadIdx.x; n < 4096; n += 256) {
        float v[8];
#pragma unroll
        for (int c = 0; c < 8; c++) v[c] = base[c * NSP + n];
#pragma unroll
        for (int c = 0; c < 8; c++)
#pragma unroll
            for (int d = 0; d < 8; d++)
                acc[c][d] = fmaf(v[c], v[d], acc[c][d]);
    }
#pragma unroll
    for (int c = 0; c < 8; c++)
#pragma unroll
        for (int d = 0; d < 8; d++)
            for (int off = 32; off > 0; off >>= 1)
                acc[c][d] += __shfl_down(acc[c][d], off);

    __shared__ float red[4][64];
    int wv = threadIdx.x >> 6;
    if ((threadIdx.x & 63) == 0) {
#pragma unroll
        for (int c = 0; c < 8; c++)
#pragma unroll
            for (int d = 0; d < 8; d++) red[wv][c * 8 + d] = acc[c][d];
    }
    __syncthreads();
    if (threadIdx.x < 64)
        Gp[(size_t)(q * 128 + bh) * 64 + threadIdx.x] =
            red[0][threadIdx.x] + red[1][threadIdx.x] + red[2][threadIdx.x] + red[3][threadIdx.x];
}

__global__ void gram_reduce(const float* __restrict__ Gp, float* __restrict__ G) {
    int bh = blockIdx.x;
    int t = threadIdx.x;
    float s = 0.f;
#pragma unroll
    for (int q = 0; q < 4; q++) s += Gp[(size_t)(q * 128 + bh) * 64 + t];
    G[bh * 64 + t] = s;
}

// ---------- softmax over 8x8 logits ----------
__global__ void softmax_kernel(const float* __restrict__ G, const float* __restrict__ temp,
                               float* __restrict__ attn) {
    int bh = blockIdx.x; int h = bh & 15;
    int t = threadIdx.x;
    int c = t >> 3, d = t & 7;
    const float* g = G + bh * 64;
    float nc = fmaxf(sqrtf(g[c * 8 + c]), EPSN);
    float nd = fmaxf(sqrtf(g[d * 8 + d]), EPSN);
    float a = g[t] / (nc * nd) * temp[h];
    float m = a;
#pragma unroll
    for (int off = 4; off > 0; off >>= 1) m = fmaxf(m, __shfl_xor(m, off));
    float e = __expf(a - m);
    float s = e;
#pragma unroll
    for (int off = 4; off > 0; off >>= 1) s += __shfl_xor(s, off);
    attn[bh * 64 + t] = e / s;
}

// ---------- av: y_t = attn @ v, NHWC bf16, coalesced writes ----------
__global__ __launch_bounds__(256) void av_v2(const float* __restrict__ x2,
                                             const float* __restrict__ attn,
                                             __hip_bfloat16* __restrict__ yt) {
    int b  = blockIdx.x >> 8;
    int p0 = (blockIdx.x & 255) << 6;       // 64 positions
    __shared__ float vt[128][65];
    __shared__ float at[16][65];
    for (int idx = threadIdx.x; idx < 1024; idx += 256)
        at[idx >> 6][idx & 63] = attn[(size_t)b * 1024 + idx];
    for (int idx = threadIdx.x; idx < 8192; idx += 256) {
        int row = idx >> 6, col = idx & 63;
        vt[row][col] = x2[(size_t)(b * 128 + row) * NSP + p0 + col];
    }
    __syncthreads();
    for (int idx = threadIdx.x; idx < 1024; idx += 256) {
        int cq = idx & 15;                  // head
        int p  = idx >> 4;                  // 0..63
        float vv[8];
#pragma unroll
        for (int d = 0; d < 8; d++) vv[d] = vt[cq * 8 + d][p];
        unsigned int pk[4];
#pragma unroll
        for (int c = 0; c < 8; c += 2) {
            float s0 = 0.f, s1 = 0.f;
#pragma unroll
            for (int d = 0; d < 8; d++) {
                s0 = fmaf(at[cq][c * 8 + d], vv[d], s0);
                s1 = fmaf(at[cq][(c + 1) * 8 + d], vv[d], s1);
            }
            pk[c >> 1] = (unsigned int)f2bf(s0) | ((unsigned int)f2bf(s1) << 16);
        }
        uint4 st; st.x = pk[0]; st.y = pk[1]; st.z = pk[2]; st.w = pk[3];
        *reinterpret_cast<uint4*>(yt + ((size_t)b * NSP + p0 + p) * 128 + cq * 8) = st;
    }
}

// ---------- fused conv block: conv1(3x3,leaky) -> conv2(1x1)->h2 ; sc(1x1)+x1 -> out ----------
// Block = (b, row h), XCD-chunk-swizzled. M=128 (w), N=128. 4 waves, 2m x 2n, 4x4 frags each.
// Weights in frag-major layout: every B-frag load = base + lane*16B (fully coalesced).
__global__ __launch_bounds__(256, 3) void fused_conv(const __hip_bfloat16* __restrict__ yt,
                                                     const __hip_bfloat16* __restrict__ wb1,
                                                     const __hip_bfloat16* __restrict__ wb2,
                                                     const __hip_bfloat16* __restrict__ wbsc,
                                                     const float* __restrict__ b1,
                                                     const float* __restrict__ b2,
                                                     const float* __restrict__ bsc,
                                                     const float* __restrict__ x1,
                                                     __hip_bfloat16* __restrict__ h2,
                                                     float* __restrict__ out) {
    __shared__ uint4 smem[3168];          // conv1 stage: [r:3][col:132][g:8]; reused as bf16 tile [128][128] swizzled
    char* smem_raw = (char*)smem;
    int bid = blockIdx.x;
    int blk = (bid & 7) * 128 + (bid >> 3);   // XCD-chunked: each XCD owns one batch image
    int b = blk >> 7, h = blk & 127;
    int tid = threadIdx.x;
    int lane = tid & 63;
    int wid = tid >> 6;
    int wm = wid >> 1, wn = wid & 1;
    int l15 = lane & 15;
    int lk = lane >> 4;

    const short8* wf1  = reinterpret_cast<const short8*>(wb1);
    const short8* wf2  = reinterpret_cast<const short8*>(wb2);
    const short8* wfsc = reinterpret_cast<const short8*>(wbsc);

    f32x4 acc[4][4];
#pragma unroll
    for (int a = 0; a < 4; a++)
#pragma unroll
        for (int c = 0; c < 4; c++) acc[a][c] = (f32x4){0.f, 0.f, 0.f, 0.f};

    // ---- conv1 ----
#pragma unroll
    for (int half = 0; half < 2; ++half) {
        __syncthreads();
        for (int idx = tid; idx < 3168; idx += 256) {
            int chunk = idx & 7;
            int colr = idx >> 3;
            int col = colr % 132;
            int r = colr / 132;
            int hh = h + r - 1;
            int w = col - 1;
            uint4 v = make_uint4(0u, 0u, 0u, 0u);
            if ((unsigned)hh < 128u && (unsigned)w < 128u)
                v = *reinterpret_cast<const uint4*>(
                    yt + (((size_t)(b * 128 + hh)) * 128 + w) * 128 + half * 64 + chunk * 8);
            smem[r * 1056 + col * 8 + (chunk ^ (col & 7))] = v;
        }
        __syncthreads();

#pragma unroll
        for (int tap = 0; tap < 9; ++tap) {
            int kh = tap / 3, kw = tap - kh * 3;
#pragma unroll
            for (int icc = 0; icc < 2; ++icc) {
                const short8* wp = wf1 + ((size_t)(((tap * 2 + half) * 2 + wn) * 2 + icc) * 4) * 64 + lane;
                short8 bfr[4];
#pragma unroll
                for (int c = 0; c < 4; ++c)
                    bfr[c] = wp[c * 64];
                short8 afr[4];
#pragma unroll
                for (int a = 0; a < 4; ++a) {
                    int col = (wm * 4 + a) * 16 + l15 + kw;
                    int g = icc * 4 + lk;
                    afr[a] = *reinterpret_cast<const short8*>(
                        &smem[kh * 1056 + col * 8 + (g ^ (col & 7))]);
                }
#pragma unroll
                for (int a = 0; a < 4; ++a)
#pragma unroll
                    for (int c = 0; c < 4; ++c)
                        acc[a][c] = __builtin_amdgcn_mfma_f32_16x16x32_bf16(
                            afr[a], bfr[c], acc[a][c], 0, 0, 0);
            }
        }
    }

    // ---- h1 = bias+leaky -> LDS bf16 tile [p][o], granule-XOR swizzled ----
    __syncthreads();   // all waves done reading conv1 stage
#pragma unroll
    for (int c = 0; c < 4; ++c) {
        int o = wn * 64 + c * 16 + l15;
        float bv = b1[o];
        int go = o >> 3, ob = (o & 7) << 1;
#pragma unroll
        for (int a = 0; a < 4; ++a) {
            int pb = (wm * 4 + a) * 16 + lk * 4;
#pragma unroll
            for (int j = 0; j < 4; ++j) {
                int p = pb + j;
                float v = acc[a][c][j] + bv;
                v = v >= 0.f ? v : SLOPE * v;
                *reinterpret_cast<__hip_bfloat16*>(
                    smem_raw + p * 256 + (((go ^ (p & 15)) << 4) | ob)) = __float2bfloat16(v);
            }
        }
    }
    __syncthreads();

    // ---- conv2: h2 = W2 @ h1 + b2  (bf16 NCHW out) ----
#pragma unroll
    for (int a = 0; a < 4; a++)
#pragma unroll
        for (int c = 0; c < 4; c++) acc[a][c] = (f32x4){0.f, 0.f, 0.f, 0.f};
#pragma unroll
    for (int kk = 0; kk < 4; ++kk) {
        short8 bfr[4];
#pragma unroll
        for (int c = 0; c < 4; ++c)
            bfr[c] = wf2[((size_t)(wn * 4 + kk) * 4 + c) * 64 + lane];
        short8 afr[4];
        int g = kk * 4 + lk;
#pragma unroll
        for (int a = 0; a < 4; ++a) {
            int p = (wm * 4 + a) * 16 + l15;
            afr[a] = *reinterpret_cast<const short8*>(smem_raw + p * 256 + ((g ^ (p & 15)) << 4));
        }
#pragma unroll
        for (int a = 0; a < 4; ++a)
#pragma unroll
            for (int c = 0; c < 4; ++c)
                acc[a][c] = __builtin_amdgcn_mfma_f32_16x16x32_bf16(afr[a], bfr[c], acc[a][c], 0, 0, 0);
    }
#pragma unroll
    for (int c = 0; c < 4; ++c) {
        int o = wn * 64 + c * 16 + l15;
        float bv = b2[o];
        size_t obase = ((size_t)(b * 128 + o) * 128 + h) * 128;
#pragma unroll
        for (int a = 0; a < 4; ++a) {
            int w0 = (wm * 4 + a) * 16 + lk * 4;
            uint2 st;
            st.x = (unsigned int)f2bf(acc[a][c][0] + bv) | ((unsigned int)f2bf(acc[a][c][1] + bv) << 16);
            st.y = (unsigned int)f2bf(acc[a][c][2] + bv) | ((unsigned int)f2bf(acc[a][c][3] + bv) << 16);
            *reinterpret_cast<uint2*>(h2 + obase + w0) = st;
        }
    }

    // ---- stage y row h into tile, then sc + x1 -> out ----
    __syncthreads();   // conv2 tile reads done
    for (int idx = tid; idx < 2048; idx += 256) {
        int p = idx >> 4, g = idx & 15;
        uint4 v = *reinterpret_cast<const uint4*>(
            yt + ((size_t)(b * NSP + h * 128 + p)) * 128 + g * 8);
        *reinterpret_cast<uint4*>(smem_raw + p * 256 + ((g ^ (p & 15)) << 4)) = v;
    }
    __syncthreads();

#pragma unroll
    for (int a = 0; a < 4; a++)
#pragma unroll
        for (int c = 0; c < 4; c++) acc[a][c] = (f32x4){0.f, 0.f, 0.f, 0.f};
#pragma unroll
    for (int kk = 0; kk < 4; ++kk) {
        short8 bfr[4];
#pragma unroll
        for (int c = 0; c < 4; ++c)
            bfr[c] = wfsc[((size_t)(wn * 4 + kk) * 4 + c) * 64 + lane];
        short8 afr[4];
        int g = kk * 4 + lk;
#pragma unroll
        for (int a = 0; a < 4; ++a) {
            int p = (wm * 4 + a) * 16 + l15;
            afr[a] = *reinterpret_cast<const short8*>(smem_raw + p * 256 + ((g ^ (p & 15)) << 4));
        }
#pragma unroll
        for (int a = 0; a < 4; ++a)
#pragma unroll
            for (int c = 0; c < 4; ++c)
                acc[a][c] = __builtin_amdgcn_mfma_f32_16x16x32_bf16(afr[a], bfr[c], acc[a][c], 0, 0, 0);
    }
#pragma unroll
    for (int c = 0; c < 4; ++c) {
        int o = wn * 64 + c * 16 + l15;
        float bv = bsc[o];
        size_t obase = ((size_t)(b * 128 + o) * 128 + h) * 128;
#pragma unroll
        for (int a = 0; a < 4; ++a) {
            int w0 = (wm * 4 + a) * 16 + lk * 4;
            float4 xv = *reinterpret_cast<const float4*>(x1 + obase + w0);
            float4 st;
            st.x = acc[a][c][0] + bv + xv.x;
            st.y = acc[a][c][1] + bv + xv.y;
            st.z = acc[a][c][2] + bv + xv.z;
            st.w = acc[a][c][3] + bv + xv.w;
            *reinterpret_cast<float4*>(out + obase + w0) = st;
        }
    }
}

// ---------- depthwise 3x3 reflect-pad + bias + LeakyReLU, out += result (bf16 h2) ----------
// 8 outputs/thread, vectorized row loads, XCD-chunk-swizzled.
__global__ __launch_bounds__(256) void dw_v2(const __hip_bfloat16* __restrict__ h2,
                                             const float* __restrict__ dww,
                                             const float* __restrict__ dwb,
                                             float* __restrict__ out) {
    int bid = blockIdx.x;                          // 8192 blocks
    int swz = (bid & 7) * 1024 + (bid >> 3);
    size_t tidx = (size_t)swz * 256 + threadIdx.x; // 2097152 threads total
    int w0 = (int)((tidx & 15) << 3);
    int hh = (int)((tidx >> 4) & 127);
    int bc = (int)(tidx >> 11);
    int c  = bc & 127;
    const __hip_bfloat16* src = h2 + ((size_t)bc << 14);
    float wg[9];
#pragma unroll
    for (int k = 0; k < 9; ++k) wg[k] = dww[c * 9 + k];
    float bv = dwb[c];
    float a8[8];
#pragma unroll
    for (int j = 0; j < 8; ++j) a8[j] = bv;
#pragma unroll
    for (int kh = 0; kh < 3; ++kh) {
        int ih = hh + kh - 1;
        ih = ih < 0 ? 1 : (ih > 127 ? 126 : ih);
        const __hip_bfloat16* row = src + ih * 128;
        short8 mid = *reinterpret_cast<const short8*>(row + w0);
        float v[10];
        v[0] = bf2f(row[w0 == 0 ? 1 : w0 - 1]);
#pragma unroll
        for (int j = 0; j < 8; ++j)
            v[j + 1] = __uint_as_float((unsigned int)(unsigned short)mid[j] << 16);
        v[9] = bf2f(row[w0 == 120 ? 126 : w0 + 8]);
#pragma unroll
        for (int kw = 0; kw < 3; ++kw)
#pragma unroll
            for (int j = 0; j < 8; ++j)
                a8[j] = fmaf(v[j + kw], wg[kh * 3 + kw], a8[j]);
    }
    size_t ob = ((size_t)bc << 14) + hh * 128 + w0;
    float4 o0 = *reinterpret_cast<const float4*>(out + ob);
    float4 o1 = *reinterpret_cast<const float4*>(out + ob + 4);
#pragma unroll
    for (int j = 0; j < 8; ++j) a8[j] = a8[j] >= 0.f ? a8[j] : SLOPE * a8[j];
    o0.x += a8[0]; o0.y += a8[1]; o0.z += a8[2]; o0.w += a8[3];
    o1.x += a8[4]; o1.y += a8[5]; o1.z += a8[6]; o1.w += a8[7];
    *reinterpret_cast<float4*>(out + ob) = o0;
    *reinterpret_cast<float4*>(out + ob + 4) = o1;
}

extern "C" void kernel_launch(void* const* d_in, const int* in_sizes, int n_in,
                              void* d_out, int out_size, void* d_ws, size_t ws_size,
                              hipStream_t stream) {
    const float* x1   = (const float*)d_in[0];
    const float* x2   = (const float*)d_in[1];
    const float* temp = (const float*)d_in[2];
    const float* c1w  = (const float*)d_in[3];
    const float* c1b  = (const float*)d_in[4];
    const float* c2w  = (const float*)d_in[5];
    const float* c2b  = (const float*)d_in[6];
    const float* dww  = (const float*)d_in[7];
    const float* dwb  = (const float*)d_in[8];
    const float* scw  = (const float*)d_in[9];
    const float* scb  = (const float*)d_in[10];
    float* out = (float*)d_out;
    char* ws = (char*)d_ws;

    float*          G    = (float*)(ws);                        // 32 KB
    float*          attn = (float*)(ws + (32 << 10));           // 32 KB
    float*          Gp   = (float*)(ws + (64 << 10));           // 128 KB
    __hip_bfloat16* wb1  = (__hip_bfloat16*)(ws + (192 << 10)); // 288 KB (frag-major)
    __hip_bfloat16* wb2  = (__hip_bfloat16*)(ws + (480 << 10)); // 32 KB  (frag-major)
    __hip_bfloat16* wbsc = (__hip_bfloat16*)(ws + (512 << 10)); // 32 KB  (frag-major)
    __hip_bfloat16* yt   = (__hip_bfloat16*)(ws + ((size_t)1 << 20));   // 32 MiB NHWC bf16
    __hip_bfloat16* h2b  = (__hip_bfloat16*)(ws + ((size_t)34 << 20));  // 32 MiB NCHW bf16

    prep_wb1<<<576, 256, 0, stream>>>(c1w, wb1);
    prep_w1x1<<<64, 256, 0, stream>>>(c2w, wb2);
    prep_w1x1<<<64, 256, 0, stream>>>(scw, wbsc);

    gram_part<<<512, 256, 0, stream>>>(x1, Gp);
    gram_reduce<<<128, 64, 0, stream>>>(Gp, G);
    softmax_kernel<<<128, 64, 0, stream>>>(G, temp, attn);
    av_v2<<<2048, 256, 0, stream>>>(x2, attn, yt);

    fused_conv<<<1024, 256, 0, stream>>>(yt, wb1, wb2, wbsc, c1b, c2b, scb, x1, h2b, out);
    dw_v2<<<8192, 256, 0, stream>>>(h2b, dww, dwb, out);
}

// Round 6
// 167.922 us; speedup vs baseline: 4.4403x; 1.0119x over previous
//
#include <hip/hip_runtime.h>
#include <hip/hip_bf16.h>

typedef __attribute__((ext_vector_type(8))) short short8;
typedef __attribute__((ext_vector_type(4))) float f32x4;

#define NB 8
#define NC 128
#define NHW 128
#define NSP (NHW*NHW)     // 16384
#define SLOPE 0.2f
#define EPSN 1e-12f

static __device__ __forceinline__ unsigned short f2bf(float f) {
    __hip_bfloat16 h = __float2bfloat16(f);
    return *reinterpret_cast<unsigned short*>(&h);
}
static __device__ __forceinline__ float bf2f(__hip_bfloat16 h) {
    return __bfloat162float(h);
}

// ---------- weight prep: FRAG-MAJOR layouts ----------
// conv1_w [o][i][3][3] fp32 -> wb1 frag-major bf16, K split in QUARTERS (32ch):
// chunk = ((tap*4 + q)*2 + wn)*4 + c ; element = chunk*512 + lane*8 + j
// i: q=i>>5, lk=(i>>3)&3, j=i&7 ; o: wn=o>>6, c=(o>>4)&3, l15=o&15 ; lane=lk*16+l15
__global__ void prep_wb1(const float* __restrict__ w, __hip_bfloat16* __restrict__ wb) {
    int idx = blockIdx.x * 256 + threadIdx.x;          // 147456
    if (idx >= 128 * 128 * 9) return;
    int kw = idx % 3; int t = idx / 3;
    int kh = t % 3;   t /= 3;
    int i  = t % 128; int o = t / 128;
    int tap = kh * 3 + kw;
    int q = i >> 5, lk = (i >> 3) & 3, j = i & 7;
    int wn = o >> 6, c = (o >> 4) & 3, l15 = o & 15;
    int lane = lk * 16 + l15;
    size_t chunk = ((size_t)(tap * 4 + q) * 2 + wn) * 4 + c;
    wb[chunk * 512 + lane * 8 + j] = __float2bfloat16(w[idx]);
}

// 1x1 w [o][i] fp32 -> frag-major bf16: chunk = ((wn*4+kk)*4+c), element = chunk*512+lane*8+j
__global__ void prep_w1x1(const float* __restrict__ w, __hip_bfloat16* __restrict__ wb) {
    int idx = blockIdx.x * 256 + threadIdx.x;          // 16384
    if (idx >= 128 * 128) return;
    int i = idx & 127, o = idx >> 7;
    int kk = i >> 5, lk = (i >> 3) & 3, j = i & 7;
    int wn = o >> 6, c = (o >> 4) & 3, l15 = o & 15;
    int lane = lk * 16 + l15;
    size_t chunk = ((size_t)(wn * 4 + kk) * 4 + c);
    wb[chunk * 512 + lane * 8 + j] = __float2bfloat16(w[idx]);
}

// ---------- gram: partial over spatial quarter ----------
__global__ __launch_bounds__(256) void gram_part(const float* __restrict__ x1,
                                                 float* __restrict__ Gp) {
    int bh = blockIdx.x & 127;
    int q  = blockIdx.x >> 7;                           // 0..3
    const float* base = x1 + (size_t)bh * 8 * NSP + q * 4096;
    float acc[8][8];
#pragma unroll
    for (int c = 0; c < 8; c++)
#pragma unroll
        for (int d = 0; d < 8; d++) acc[c][d] = 0.f;

    for (int n = threadIdx.x; n < 4096; n += 256) {
        float v[8];
#pragma unroll
        for (int c = 0; c < 8; c++) v[c] = base[c * NSP + n];
#pragma unroll
        for (int c = 0; c < 8; c++)
#pragma unroll
            for (int d = 0; d < 8; d++)
                acc[c][d] = fmaf(v[c], v[d], acc[c][d]);
    }
#pragma unroll
    for (int c = 0; c < 8; c++)
#pragma unroll
        for (int d = 0; d < 8; d++)
            for (int off = 32; off > 0; off >>= 1)
                acc[c][d] += __shfl_down(acc[c][d], off);

    __shared__ float red[4][64];
    int wv = threadIdx.x >> 6;
    if ((threadIdx.x & 63) == 0) {
#pragma unroll
        for (int c = 0; c < 8; c++)
#pragma unroll
            for (int d = 0; d < 8; d++) red[wv][c * 8 + d] = acc[c][d];
    }
    __syncthreads();
    if (threadIdx.x < 64)
        Gp[(size_t)(q * 128 + bh) * 64 + threadIdx.x] =
            red[0][threadIdx.x] + red[1][threadIdx.x] + red[2][threadIdx.x] + red[3][threadIdx.x];
}

__global__ void gram_reduce(const float* __restrict__ Gp, float* __restrict__ G) {
    int bh = blockIdx.x;
    int t = threadIdx.x;
    float s = 0.f;
#pragma unroll
    for (int q = 0; q < 4; q++) s += Gp[(size_t)(q * 128 + bh) * 64 + t];
    G[bh * 64 + t] = s;
}

// ---------- softmax over 8x8 logits ----------
__global__ void softmax_kernel(const float* __restrict__ G, const float* __restrict__ temp,
                               float* __restrict__ attn) {
    int bh = blockIdx.x; int h = bh & 15;
    int t = threadIdx.x;
    int c = t >> 3, d = t & 7;
    const float* g = G + bh * 64;
    float nc = fmaxf(sqrtf(g[c * 8 + c]), EPSN);
    float nd = fmaxf(sqrtf(g[d * 8 + d]), EPSN);
    float a = g[t] / (nc * nd) * temp[h];
    float m = a;
#pragma unroll
    for (int off = 4; off > 0; off >>= 1) m = fmaxf(m, __shfl_xor(m, off));
    float e = __expf(a - m);
    float s = e;
#pragma unroll
    for (int off = 4; off > 0; off >>= 1) s += __shfl_xor(s, off);
    attn[bh * 64 + t] = e / s;
}

// ---------- av: y_t = attn @ v, NHWC bf16, coalesced writes ----------
__global__ __launch_bounds__(256) void av_v2(const float* __restrict__ x2,
                                             const float* __restrict__ attn,
                                             __hip_bfloat16* __restrict__ yt) {
    int b  = blockIdx.x >> 8;
    int p0 = (blockIdx.x & 255) << 6;       // 64 positions
    __shared__ float vt[128][65];
    __shared__ float at[16][65];
    for (int idx = threadIdx.x; idx < 1024; idx += 256)
        at[idx >> 6][idx & 63] = attn[(size_t)b * 1024 + idx];
    for (int idx = threadIdx.x; idx < 8192; idx += 256) {
        int row = idx >> 6, col = idx & 63;
        vt[row][col] = x2[(size_t)(b * 128 + row) * NSP + p0 + col];
    }
    __syncthreads();
    for (int idx = threadIdx.x; idx < 1024; idx += 256) {
        int cq = idx & 15;                  // head
        int p  = idx >> 4;                  // 0..63
        float vv[8];
#pragma unroll
        for (int d = 0; d < 8; d++) vv[d] = vt[cq * 8 + d][p];
        unsigned int pk[4];
#pragma unroll
        for (int c = 0; c < 8; c += 2) {
            float s0 = 0.f, s1 = 0.f;
#pragma unroll
            for (int d = 0; d < 8; d++) {
                s0 = fmaf(at[cq][c * 8 + d], vv[d], s0);
                s1 = fmaf(at[cq][(c + 1) * 8 + d], vv[d], s1);
            }
            pk[c >> 1] = (unsigned int)f2bf(s0) | ((unsigned int)f2bf(s1) << 16);
        }
        uint4 st; st.x = pk[0]; st.y = pk[1]; st.z = pk[2]; st.w = pk[3];
        *reinterpret_cast<uint4*>(yt + ((size_t)b * NSP + p0 + p) * 128 + cq * 8) = st;
    }
}

// ---------- fused conv block: conv1(3x3,leaky) -> conv2(1x1)->h2 ; sc(1x1)+x1 -> out ----------
// Block = (b, row h), XCD-chunk-swizzled. M=128 (w), N=128. 4 waves, 2m x 2n, 4x4 frags each.
// conv1 staged in K-QUARTERS (32 ch): LDS 25.3 KB stage / 32 KB total -> 5 blocks/CU cap,
// so all 4 grid-blocks per CU stay resident (TLP hides weight-load latency).
__global__ __launch_bounds__(256, 4) void fused_conv(const __hip_bfloat16* __restrict__ yt,
                                                     const __hip_bfloat16* __restrict__ wb1,
                                                     const __hip_bfloat16* __restrict__ wb2,
                                                     const __hip_bfloat16* __restrict__ wbsc,
                                                     const float* __restrict__ b1,
                                                     const float* __restrict__ b2,
                                                     const float* __restrict__ bsc,
                                                     const float* __restrict__ x1,
                                                     __hip_bfloat16* __restrict__ h2,
                                                     float* __restrict__ out) {
    __shared__ uint4 smem[2048];          // 32 KB: conv1 quarter-stage [r:3][col:132][g:4] (25.3 KB); bf16 tile [128][256B]
    char* smem_raw = (char*)smem;
    int bid = blockIdx.x;
    int blk = (bid & 7) * 128 + (bid >> 3);   // XCD-chunked: each XCD owns one batch image
    int b = blk >> 7, h = blk & 127;
    int tid = threadIdx.x;
    int lane = tid & 63;
    int wid = tid >> 6;
    int wm = wid >> 1, wn = wid & 1;
    int l15 = lane & 15;
    int lk = lane >> 4;

    const short8* wf1  = reinterpret_cast<const short8*>(wb1);
    const short8* wf2  = reinterpret_cast<const short8*>(wb2);
    const short8* wfsc = reinterpret_cast<const short8*>(wbsc);

    f32x4 acc[4][4];
#pragma unroll
    for (int a = 0; a < 4; a++)
#pragma unroll
        for (int c = 0; c < 4; c++) acc[a][c] = (f32x4){0.f, 0.f, 0.f, 0.f};

    // ---- conv1: 4 K-quarters of 32 channels ----
#pragma unroll
    for (int q = 0; q < 4; ++q) {
        __syncthreads();
        for (int idx = tid; idx < 1584; idx += 256) {   // 3 rows x 132 cols x 4 granules
            int g = idx & 3;
            int colr = idx >> 2;
            int col = colr % 132;
            int r = colr / 132;
            int hh = h + r - 1;
            int w = col - 1;
            uint4 v = make_uint4(0u, 0u, 0u, 0u);
            if ((unsigned)hh < 128u && (unsigned)w < 128u)
                v = *reinterpret_cast<const uint4*>(
                    yt + (((size_t)(b * 128 + hh)) * 128 + w) * 128 + q * 32 + g * 8);
            smem[r * 528 + col * 4 + (g ^ (col & 3))] = v;
        }
        __syncthreads();

#pragma unroll
        for (int tap = 0; tap < 9; ++tap) {
            int kh = tap / 3, kw = tap - kh * 3;
            const short8* wp = wf1 + ((size_t)((tap * 4 + q) * 2 + wn) * 4) * 64 + lane;
            short8 bfr[4];
#pragma unroll
            for (int c = 0; c < 4; ++c)
                bfr[c] = wp[c * 64];
            short8 afr[4];
#pragma unroll
            for (int a = 0; a < 4; ++a) {
                int col = (wm * 4 + a) * 16 + l15 + kw;
                afr[a] = *reinterpret_cast<const short8*>(
                    &smem[kh * 528 + col * 4 + (lk ^ (col & 3))]);
            }
#pragma unroll
            for (int a = 0; a < 4; ++a)
#pragma unroll
                for (int c = 0; c < 4; ++c)
                    acc[a][c] = __builtin_amdgcn_mfma_f32_16x16x32_bf16(
                        afr[a], bfr[c], acc[a][c], 0, 0, 0);
        }
    }

    // ---- h1 = bias+leaky -> LDS bf16 tile [p][o], granule-XOR swizzled ----
    __syncthreads();   // all waves done reading conv1 stage
#pragma unroll
    for (int c = 0; c < 4; ++c) {
        int o = wn * 64 + c * 16 + l15;
        float bv = b1[o];
        int go = o >> 3, ob = (o & 7) << 1;
#pragma unroll
        for (int a = 0; a < 4; ++a) {
            int pb = (wm * 4 + a) * 16 + lk * 4;
#pragma unroll
            for (int j = 0; j < 4; ++j) {
                int p = pb + j;
                float v = acc[a][c][j] + bv;
                v = v >= 0.f ? v : SLOPE * v;
                *reinterpret_cast<__hip_bfloat16*>(
                    smem_raw + p * 256 + (((go ^ (p & 15)) << 4) | ob)) = __float2bfloat16(v);
            }
        }
    }
    __syncthreads();

    // ---- conv2: h2 = W2 @ h1 + b2  (bf16 NCHW out) ----
#pragma unroll
    for (int a = 0; a < 4; a++)
#pragma unroll
        for (int c = 0; c < 4; c++) acc[a][c] = (f32x4){0.f, 0.f, 0.f, 0.f};
#pragma unroll
    for (int kk = 0; kk < 4; ++kk) {
        short8 bfr[4];
#pragma unroll
        for (int c = 0; c < 4; ++c)
            bfr[c] = wf2[((size_t)(wn * 4 + kk) * 4 + c) * 64 + lane];
        short8 afr[4];
        int g = kk * 4 + lk;
#pragma unroll
        for (int a = 0; a < 4; ++a) {
            int p = (wm * 4 + a) * 16 + l15;
            afr[a] = *reinterpret_cast<const short8*>(smem_raw + p * 256 + ((g ^ (p & 15)) << 4));
        }
#pragma unroll
        for (int a = 0; a < 4; ++a)
#pragma unroll
            for (int c = 0; c < 4; ++c)
                acc[a][c] = __builtin_amdgcn_mfma_f32_16x16x32_bf16(afr[a], bfr[c], acc[a][c], 0, 0, 0);
    }
#pragma unroll
    for (int c = 0; c < 4; ++c) {
        int o = wn * 64 + c * 16 + l15;
        float bv = b2[o];
        size_t obase = ((size_t)(b * 128 + o) * 128 + h) * 128;
#pragma unroll
        for (int a = 0; a < 4; ++a) {
            int w0 = (wm * 4 + a) * 16 + lk * 4;
            uint2 st;
            st.x = (unsigned int)f2bf(acc[a][c][0] + bv) | ((unsigned int)f2bf(acc[a][c][1] + bv) << 16);
            st.y = (unsigned int)f2bf(acc[a][c][2] + bv) | ((unsigned int)f2bf(acc[a][c][3] + bv) << 16);
            *reinterpret_cast<uint2*>(h2 + obase + w0) = st;
        }
    }

    // ---- stage y row h into tile, then sc + x1 -> out ----
    __syncthreads();   // conv2 tile reads done
    for (int idx = tid; idx < 2048; idx += 256) {
        int p = idx >> 4, g = idx & 15;
        uint4 v = *reinterpret_cast<const uint4*>(
            yt + ((size_t)(b * NSP + h * 128 + p)) * 128 + g * 8);
        *reinterpret_cast<uint4*>(smem_raw + p * 256 + ((g ^ (p & 15)) << 4)) = v;
    }
    __syncthreads();

#pragma unroll
    for (int a = 0; a < 4; a++)
#pragma unroll
        for (int c = 0; c < 4; c++) acc[a][c] = (f32x4){0.f, 0.f, 0.f, 0.f};
#pragma unroll
    for (int kk = 0; kk < 4; ++kk) {
        short8 bfr[4];
#pragma unroll
        for (int c = 0; c < 4; ++c)
            bfr[c] = wfsc[((size_t)(wn * 4 + kk) * 4 + c) * 64 + lane];
        short8 afr[4];
        int g = kk * 4 + lk;
#pragma unroll
        for (int a = 0; a < 4; ++a) {
            int p = (wm * 4 + a) * 16 + l15;
            afr[a] = *reinterpret_cast<const short8*>(smem_raw + p * 256 + ((g ^ (p & 15)) << 4));
        }
#pragma unroll
        for (int a = 0; a < 4; ++a)
#pragma unroll
            for (int c = 0; c < 4; ++c)
                acc[a][c] = __builtin_amdgcn_mfma_f32_16x16x32_bf16(afr[a], bfr[c], acc[a][c], 0, 0, 0);
    }
#pragma unroll
    for (int c = 0; c < 4; ++c) {
        int o = wn * 64 + c * 16 + l15;
        float bv = bsc[o];
        size_t obase = ((size_t)(b * 128 + o) * 128 + h) * 128;
#pragma unroll
        for (int a = 0; a < 4; ++a) {
            int w0 = (wm * 4 + a) * 16 + lk * 4;
            float4 xv = *reinterpret_cast<const float4*>(x1 + obase + w0);
            float4 st;
            st.x = acc[a][c][0] + bv + xv.x;
            st.y = acc[a][c][1] + bv + xv.y;
            st.z = acc[a][c][2] + bv + xv.z;
            st.w = acc[a][c][3] + bv + xv.w;
            *reinterpret_cast<float4*>(out + obase + w0) = st;
        }
    }
}

// ---------- depthwise 3x3 reflect-pad + bias + LeakyReLU, out += result (bf16 h2) ----------
// 8 outputs/thread, vectorized row loads, XCD-chunk-swizzled.
__global__ __launch_bounds__(256) void dw_v2(const __hip_bfloat16* __restrict__ h2,
                                             const float* __restrict__ dww,
                                             const float* __restrict__ dwb,
                                             float* __restrict__ out) {
    int bid = blockIdx.x;                          // 8192 blocks
    int swz = (bid & 7) * 1024 + (bid >> 3);
    size_t tidx = (size_t)swz * 256 + threadIdx.x; // 2097152 threads total
    int w0 = (int)((tidx & 15) << 3);
    int hh = (int)((tidx >> 4) & 127);
    int bc = (int)(tidx >> 11);
    int c  = bc & 127;
    const __hip_bfloat16* src = h2 + ((size_t)bc << 14);
    float wg[9];
#pragma unroll
    for (int k = 0; k < 9; ++k) wg[k] = dww[c * 9 + k];
    float bv = dwb[c];
    float a8[8];
#pragma unroll
    for (int j = 0; j < 8; ++j) a8[j] = bv;
#pragma unroll
    for (int kh = 0; kh < 3; ++kh) {
        int ih = hh + kh - 1;
        ih = ih < 0 ? 1 : (ih > 127 ? 126 : ih);
        const __hip_bfloat16* row = src + ih * 128;
        short8 mid = *reinterpret_cast<const short8*>(row + w0);
        float v[10];
        v[0] = bf2f(row[w0 == 0 ? 1 : w0 - 1]);
#pragma unroll
        for (int j = 0; j < 8; ++j)
            v[j + 1] = __uint_as_float((unsigned int)(unsigned short)mid[j] << 16);
        v[9] = bf2f(row[w0 == 120 ? 126 : w0 + 8]);
#pragma unroll
        for (int kw = 0; kw < 3; ++kw)
#pragma unroll
            for (int j = 0; j < 8; ++j)
                a8[j] = fmaf(v[j + kw], wg[kh * 3 + kw], a8[j]);
    }
    size_t ob = ((size_t)bc << 14) + hh * 128 + w0;
    float4 o0 = *reinterpret_cast<const float4*>(out + ob);
    float4 o1 = *reinterpret_cast<const float4*>(out + ob + 4);
#pragma unroll
    for (int j = 0; j < 8; ++j) a8[j] = a8[j] >= 0.f ? a8[j] : SLOPE * a8[j];
    o0.x += a8[0]; o0.y += a8[1]; o0.z += a8[2]; o0.w += a8[3];
    o1.x += a8[4]; o1.y += a8[5]; o1.z += a8[6]; o1.w += a8[7];
    *reinterpret_cast<float4*>(out + ob) = o0;
    *reinterpret_cast<float4*>(out + ob + 4) = o1;
}

extern "C" void kernel_launch(void* const* d_in, const int* in_sizes, int n_in,
                              void* d_out, int out_size, void* d_ws, size_t ws_size,
                              hipStream_t stream) {
    const float* x1   = (const float*)d_in[0];
    const float* x2   = (const float*)d_in[1];
    const float* temp = (const float*)d_in[2];
    const float* c1w  = (const float*)d_in[3];
    const float* c1b  = (const float*)d_in[4];
    const float* c2w  = (const float*)d_in[5];
    const float* c2b  = (const float*)d_in[6];
    const float* dww  = (const float*)d_in[7];
    const float* dwb  = (const float*)d_in[8];
    const float* scw  = (const float*)d_in[9];
    const float* scb  = (const float*)d_in[10];
    float* out = (float*)d_out;
    char* ws = (char*)d_ws;

    float*          G    = (float*)(ws);                        // 32 KB
    float*          attn = (float*)(ws + (32 << 10));           // 32 KB
    float*          Gp   = (float*)(ws + (64 << 10));           // 128 KB
    __hip_bfloat16* wb1  = (__hip_bfloat16*)(ws + (192 << 10)); // 288 KB (frag-major, quartered)
    __hip_bfloat16* wb2  = (__hip_bfloat16*)(ws + (480 << 10)); // 32 KB  (frag-major)
    __hip_bfloat16* wbsc = (__hip_bfloat16*)(ws + (512 << 10)); // 32 KB  (frag-major)
    __hip_bfloat16* yt   = (__hip_bfloat16*)(ws + ((size_t)1 << 20));   // 32 MiB NHWC bf16
    __hip_bfloat16* h2b  = (__hip_bfloat16*)(ws + ((size_t)34 << 20));  // 32 MiB NCHW bf16

    prep_wb1<<<576, 256, 0, stream>>>(c1w, wb1);
    prep_w1x1<<<64, 256, 0, stream>>>(c2w, wb2);
    prep_w1x1<<<64, 256, 0, stream>>>(scw, wbsc);

    gram_part<<<512, 256, 0, stream>>>(x1, Gp);
    gram_reduce<<<128, 64, 0, stream>>>(Gp, G);
    softmax_kernel<<<128, 64, 0, stream>>>(G, temp, attn);
    av_v2<<<2048, 256, 0, stream>>>(x2, attn, yt);

    fused_conv<<<1024, 256, 0, stream>>>(yt, wb1, wb2, wbsc, c1b, c2b, scb, x1, h2b, out);
    dw_v2<<<8192, 256, 0, stream>>>(h2b, dww, dwb, out);
}

// Round 7
// 159.779 us; speedup vs baseline: 4.6666x; 1.0510x over previous
//
#include <hip/hip_runtime.h>
#include <hip/hip_bf16.h>

typedef __attribute__((ext_vector_type(8))) short short8;
typedef __attribute__((ext_vector_type(4))) float f32x4;

#define NB 8
#define NC 128
#define NHW 128
#define NSP (NHW*NHW)     // 16384
#define SLOPE 0.2f
#define EPSN 1e-12f

static __device__ __forceinline__ unsigned short f2bf(float f) {
    __hip_bfloat16 h = __float2bfloat16(f);
    return *reinterpret_cast<unsigned short*>(&h);
}
static __device__ __forceinline__ float bf2f(__hip_bfloat16 h) {
    return __bfloat162float(h);
}

// ---------- weight prep: FRAG-MAJOR layouts ----------
// conv1_w [o][i][3][3] fp32 -> wb1 frag-major bf16, K split in QUARTERS (32ch):
// chunk = ((tap*4 + q)*2 + wn)*4 + c ; element = chunk*512 + lane*8 + j
__global__ void prep_wb1(const float* __restrict__ w, __hip_bfloat16* __restrict__ wb) {
    int idx = blockIdx.x * 256 + threadIdx.x;          // 147456
    if (idx >= 128 * 128 * 9) return;
    int kw = idx % 3; int t = idx / 3;
    int kh = t % 3;   t /= 3;
    int i  = t % 128; int o = t / 128;
    int tap = kh * 3 + kw;
    int q = i >> 5, lk = (i >> 3) & 3, j = i & 7;
    int wn = o >> 6, c = (o >> 4) & 3, l15 = o & 15;
    int lane = lk * 16 + l15;
    size_t chunk = ((size_t)(tap * 4 + q) * 2 + wn) * 4 + c;
    wb[chunk * 512 + lane * 8 + j] = __float2bfloat16(w[idx]);
}

// 1x1 w [o][i] fp32 -> frag-major bf16: chunk = ((wn*4+kk)*4+c), element = chunk*512+lane*8+j
__global__ void prep_w1x1(const float* __restrict__ w, __hip_bfloat16* __restrict__ wb) {
    int idx = blockIdx.x * 256 + threadIdx.x;          // 16384
    if (idx >= 128 * 128) return;
    int i = idx & 127, o = idx >> 7;
    int kk = i >> 5, lk = (i >> 3) & 3, j = i & 7;
    int wn = o >> 6, c = (o >> 4) & 3, l15 = o & 15;
    int lane = lk * 16 + l15;
    size_t chunk = ((size_t)(wn * 4 + kk) * 4 + c);
    wb[chunk * 512 + lane * 8 + j] = __float2bfloat16(w[idx]);
}

// ---------- gram: partial over spatial quarter ----------
__global__ __launch_bounds__(256) void gram_part(const float* __restrict__ x1,
                                                 float* __restrict__ Gp) {
    int bh = blockIdx.x & 127;
    int q  = blockIdx.x >> 7;                           // 0..3
    const float* base = x1 + (size_t)bh * 8 * NSP + q * 4096;
    float acc[8][8];
#pragma unroll
    for (int c = 0; c < 8; c++)
#pragma unroll
        for (int d = 0; d < 8; d++) acc[c][d] = 0.f;

    for (int n = threadIdx.x; n < 4096; n += 256) {
        float v[8];
#pragma unroll
        for (int c = 0; c < 8; c++) v[c] = base[c * NSP + n];
#pragma unroll
        for (int c = 0; c < 8; c++)
#pragma unroll
            for (int d = 0; d < 8; d++)
                acc[c][d] = fmaf(v[c], v[d], acc[c][d]);
    }
#pragma unroll
    for (int c = 0; c < 8; c++)
#pragma unroll
        for (int d = 0; d < 8; d++)
            for (int off = 32; off > 0; off >>= 1)
                acc[c][d] += __shfl_down(acc[c][d], off);

    __shared__ float red[4][64];
    int wv = threadIdx.x >> 6;
    if ((threadIdx.x & 63) == 0) {
#pragma unroll
        for (int c = 0; c < 8; c++)
#pragma unroll
            for (int d = 0; d < 8; d++) red[wv][c * 8 + d] = acc[c][d];
    }
    __syncthreads();
    if (threadIdx.x < 64)
        Gp[(size_t)(q * 128 + bh) * 64 + threadIdx.x] =
            red[0][threadIdx.x] + red[1][threadIdx.x] + red[2][threadIdx.x] + red[3][threadIdx.x];
}

__global__ void gram_reduce(const float* __restrict__ Gp, float* __restrict__ G) {
    int bh = blockIdx.x;
    int t = threadIdx.x;
    float s = 0.f;
#pragma unroll
    for (int q = 0; q < 4; q++) s += Gp[(size_t)(q * 128 + bh) * 64 + t];
    G[bh * 64 + t] = s;
}

// ---------- softmax over 8x8 logits ----------
__global__ void softmax_kernel(const float* __restrict__ G, const float* __restrict__ temp,
                               float* __restrict__ attn) {
    int bh = blockIdx.x; int h = bh & 15;
    int t = threadIdx.x;
    int c = t >> 3, d = t & 7;
    const float* g = G + bh * 64;
    float nc = fmaxf(sqrtf(g[c * 8 + c]), EPSN);
    float nd = fmaxf(sqrtf(g[d * 8 + d]), EPSN);
    float a = g[t] / (nc * nd) * temp[h];
    float m = a;
#pragma unroll
    for (int off = 4; off > 0; off >>= 1) m = fmaxf(m, __shfl_xor(m, off));
    float e = __expf(a - m);
    float s = e;
#pragma unroll
    for (int off = 4; off > 0; off >>= 1) s += __shfl_xor(s, off);
    attn[bh * 64 + t] = e / s;
}

// ---------- av: y_t = attn @ v, NHWC bf16, coalesced writes ----------
__global__ __launch_bounds__(256) void av_v2(const float* __restrict__ x2,
                                             const float* __restrict__ attn,
                                             __hip_bfloat16* __restrict__ yt) {
    int b  = blockIdx.x >> 8;
    int p0 = (blockIdx.x & 255) << 6;       // 64 positions
    __shared__ float vt[128][65];
    __shared__ float at[16][65];
    for (int idx = threadIdx.x; idx < 1024; idx += 256)
        at[idx >> 6][idx & 63] = attn[(size_t)b * 1024 + idx];
    for (int idx = threadIdx.x; idx < 8192; idx += 256) {
        int row = idx >> 6, col = idx & 63;
        vt[row][col] = x2[(size_t)(b * 128 + row) * NSP + p0 + col];
    }
    __syncthreads();
    for (int idx = threadIdx.x; idx < 1024; idx += 256) {
        int cq = idx & 15;                  // head
        int p  = idx >> 4;                  // 0..63
        float vv[8];
#pragma unroll
        for (int d = 0; d < 8; d++) vv[d] = vt[cq * 8 + d][p];
        unsigned int pk[4];
#pragma unroll
        for (int c = 0; c < 8; c += 2) {
            float s0 = 0.f, s1 = 0.f;
#pragma unroll
            for (int d = 0; d < 8; d++) {
                s0 = fmaf(at[cq][c * 8 + d], vv[d], s0);
                s1 = fmaf(at[cq][(c + 1) * 8 + d], vv[d], s1);
            }
            pk[c >> 1] = (unsigned int)f2bf(s0) | ((unsigned int)f2bf(s1) << 16);
        }
        uint4 st; st.x = pk[0]; st.y = pk[1]; st.z = pk[2]; st.w = pk[3];
        *reinterpret_cast<uint4*>(yt + ((size_t)b * NSP + p0 + p) * 128 + cq * 8) = st;
    }
}

// ---------- fused conv block: conv1(3x3,leaky) -> conv2(1x1)->h2 ; sc(1x1)+x1 -> out ----------
// Block = (b, row h), XCD-chunk-swizzled. M=128 (w), N=128. 4 waves, 2m x 2n, 4x4 frags each.
// conv1 staged in K-QUARTERS, plane-major LDS [r:3][g:4][col:132] (conflict-free both sides).
// B-weights depth-1 register-prefetched (named scalars, fully unrolled -> no scratch).
__global__ __launch_bounds__(256, 3) void fused_conv(const __hip_bfloat16* __restrict__ yt,
                                                     const __hip_bfloat16* __restrict__ wb1,
                                                     const __hip_bfloat16* __restrict__ wb2,
                                                     const __hip_bfloat16* __restrict__ wbsc,
                                                     const float* __restrict__ b1,
                                                     const float* __restrict__ b2,
                                                     const float* __restrict__ bsc,
                                                     const float* __restrict__ x1,
                                                     __hip_bfloat16* __restrict__ h2,
                                                     float* __restrict__ out) {
    __shared__ uint4 smem[2048];          // 32 KB: conv1 quarter-stage 3*4*132=1584 chunks (25.3 KB); bf16 tile 128x256B
    char* smem_raw = (char*)smem;
    int bid = blockIdx.x;
    int blk = (bid & 7) * 128 + (bid >> 3);   // XCD-chunked: each XCD owns one batch image
    int b = blk >> 7, h = blk & 127;
    int tid = threadIdx.x;
    int lane = tid & 63;
    int wid = tid >> 6;
    int wm = wid >> 1, wn = wid & 1;
    int l15 = lane & 15;
    int lk = lane >> 4;

    const short8* wf1  = reinterpret_cast<const short8*>(wb1);
    const short8* wf2  = reinterpret_cast<const short8*>(wb2);
    const short8* wfsc = reinterpret_cast<const short8*>(wbsc);

    f32x4 acc[4][4];
#pragma unroll
    for (int a = 0; a < 4; a++)
#pragma unroll
        for (int c = 0; c < 4; c++) acc[a][c] = (f32x4){0.f, 0.f, 0.f, 0.f};

    // ---- conv1: 4 K-quarters of 32 channels ----
#pragma unroll
    for (int q = 0; q < 4; ++q) {
        __syncthreads();
        // stage: g fast (global 64B-contiguous per position), chunk=(r*4+g)*132+col (banks uniform)
        for (int idx = tid; idx < 1584; idx += 256) {
            int g = idx & 3;
            int colr = idx >> 2;
            int col = colr % 132;
            int r = colr / 132;
            int hh = h + r - 1;
            int w = col - 1;
            uint4 v = make_uint4(0u, 0u, 0u, 0u);
            if ((unsigned)hh < 128u && (unsigned)w < 128u)
                v = *reinterpret_cast<const uint4*>(
                    yt + (((size_t)(b * 128 + hh)) * 128 + w) * 128 + q * 32 + g * 8);
            smem[(r * 4 + g) * 132 + col] = v;
        }
        __syncthreads();

        const short8* wp0 = wf1 + ((size_t)((0 * 4 + q) * 2 + wn) * 4) * 64 + lane;
        short8 cb0 = wp0[0], cb1 = wp0[64], cb2 = wp0[128], cb3 = wp0[192];

#pragma unroll
        for (int tap = 0; tap < 9; ++tap) {
            int kh = tap / 3, kw = tap - kh * 3;
            short8 nb0, nb1, nb2, nb3;
            if (tap < 8) {
                const short8* wpn = wf1 + ((size_t)(((tap + 1) * 4 + q) * 2 + wn) * 4) * 64 + lane;
                nb0 = wpn[0]; nb1 = wpn[64]; nb2 = wpn[128]; nb3 = wpn[192];
            }
            short8 afr[4];
#pragma unroll
            for (int a = 0; a < 4; ++a) {
                int col = (wm * 4 + a) * 16 + l15 + kw;
                afr[a] = *reinterpret_cast<const short8*>(&smem[(kh * 4 + lk) * 132 + col]);
            }
            __builtin_amdgcn_s_setprio(1);
#pragma unroll
            for (int a = 0; a < 4; ++a) {
                acc[a][0] = __builtin_amdgcn_mfma_f32_16x16x32_bf16(afr[a], cb0, acc[a][0], 0, 0, 0);
                acc[a][1] = __builtin_amdgcn_mfma_f32_16x16x32_bf16(afr[a], cb1, acc[a][1], 0, 0, 0);
                acc[a][2] = __builtin_amdgcn_mfma_f32_16x16x32_bf16(afr[a], cb2, acc[a][2], 0, 0, 0);
                acc[a][3] = __builtin_amdgcn_mfma_f32_16x16x32_bf16(afr[a], cb3, acc[a][3], 0, 0, 0);
            }
            __builtin_amdgcn_s_setprio(0);
            if (tap < 8) { cb0 = nb0; cb1 = nb1; cb2 = nb2; cb3 = nb3; }
        }
    }

    // ---- h1 = bias+leaky -> LDS bf16 tile [p][o], granule-XOR swizzled ----
    __syncthreads();   // all waves done reading conv1 stage
#pragma unroll
    for (int c = 0; c < 4; ++c) {
        int o = wn * 64 + c * 16 + l15;
        float bv = b1[o];
        int go = o >> 3, ob = (o & 7) << 1;
#pragma unroll
        for (int a = 0; a < 4; ++a) {
            int pb = (wm * 4 + a) * 16 + lk * 4;
#pragma unroll
            for (int j = 0; j < 4; ++j) {
                int p = pb + j;
                float v = acc[a][c][j] + bv;
                v = v >= 0.f ? v : SLOPE * v;
                *reinterpret_cast<__hip_bfloat16*>(
                    smem_raw + p * 256 + (((go ^ (p & 15)) << 4) | ob)) = __float2bfloat16(v);
            }
        }
    }
    __syncthreads();

    // ---- conv2: h2 = W2 @ h1 + b2  (bf16 NCHW out) ----
#pragma unroll
    for (int a = 0; a < 4; a++)
#pragma unroll
        for (int c = 0; c < 4; c++) acc[a][c] = (f32x4){0.f, 0.f, 0.f, 0.f};
#pragma unroll
    for (int kk = 0; kk < 4; ++kk) {
        short8 bfr[4];
#pragma unroll
        for (int c = 0; c < 4; ++c)
            bfr[c] = wf2[((size_t)(wn * 4 + kk) * 4 + c) * 64 + lane];
        short8 afr[4];
        int g = kk * 4 + lk;
#pragma unroll
        for (int a = 0; a < 4; ++a) {
            int p = (wm * 4 + a) * 16 + l15;
            afr[a] = *reinterpret_cast<const short8*>(smem_raw + p * 256 + ((g ^ (p & 15)) << 4));
        }
        __builtin_amdgcn_s_setprio(1);
#pragma unroll
        for (int a = 0; a < 4; ++a)
#pragma unroll
            for (int c = 0; c < 4; ++c)
                acc[a][c] = __builtin_amdgcn_mfma_f32_16x16x32_bf16(afr[a], bfr[c], acc[a][c], 0, 0, 0);
        __builtin_amdgcn_s_setprio(0);
    }
#pragma unroll
    for (int c = 0; c < 4; ++c) {
        int o = wn * 64 + c * 16 + l15;
        float bv = b2[o];
        size_t obase = ((size_t)(b * 128 + o) * 128 + h) * 128;
#pragma unroll
        for (int a = 0; a < 4; ++a) {
            int w0 = (wm * 4 + a) * 16 + lk * 4;
            uint2 st;
            st.x = (unsigned int)f2bf(acc[a][c][0] + bv) | ((unsigned int)f2bf(acc[a][c][1] + bv) << 16);
            st.y = (unsigned int)f2bf(acc[a][c][2] + bv) | ((unsigned int)f2bf(acc[a][c][3] + bv) << 16);
            *reinterpret_cast<uint2*>(h2 + obase + w0) = st;
        }
    }

    // ---- stage y row h into tile, then sc + x1 -> out ----
    __syncthreads();   // conv2 tile reads done
    for (int idx = tid; idx < 2048; idx += 256) {
        int p = idx >> 4, g = idx & 15;
        uint4 v = *reinterpret_cast<const uint4*>(
            yt + ((size_t)(b * NSP + h * 128 + p)) * 128 + g * 8);
        *reinterpret_cast<uint4*>(smem_raw + p * 256 + ((g ^ (p & 15)) << 4)) = v;
    }
    __syncthreads();

#pragma unroll
    for (int a = 0; a < 4; a++)
#pragma unroll
        for (int c = 0; c < 4; c++) acc[a][c] = (f32x4){0.f, 0.f, 0.f, 0.f};
#pragma unroll
    for (int kk = 0; kk < 4; ++kk) {
        short8 bfr[4];
#pragma unroll
        for (int c = 0; c < 4; ++c)
            bfr[c] = wfsc[((size_t)(wn * 4 + kk) * 4 + c) * 64 + lane];
        short8 afr[4];
        int g = kk * 4 + lk;
#pragma unroll
        for (int a = 0; a < 4; ++a) {
            int p = (wm * 4 + a) * 16 + l15;
            afr[a] = *reinterpret_cast<const short8*>(smem_raw + p * 256 + ((g ^ (p & 15)) << 4));
        }
        __builtin_amdgcn_s_setprio(1);
#pragma unroll
        for (int a = 0; a < 4; ++a)
#pragma unroll
            for (int c = 0; c < 4; ++c)
                acc[a][c] = __builtin_amdgcn_mfma_f32_16x16x32_bf16(afr[a], bfr[c], acc[a][c], 0, 0, 0);
        __builtin_amdgcn_s_setprio(0);
    }
#pragma unroll
    for (int c = 0; c < 4; ++c) {
        int o = wn * 64 + c * 16 + l15;
        float bv = bsc[o];
        size_t obase = ((size_t)(b * 128 + o) * 128 + h) * 128;
#pragma unroll
        for (int a = 0; a < 4; ++a) {
            int w0 = (wm * 4 + a) * 16 + lk * 4;
            float4 xv = *reinterpret_cast<const float4*>(x1 + obase + w0);
            float4 st;
            st.x = acc[a][c][0] + bv + xv.x;
            st.y = acc[a][c][1] + bv + xv.y;
            st.z = acc[a][c][2] + bv + xv.z;
            st.w = acc[a][c][3] + bv + xv.w;
            *reinterpret_cast<float4*>(out + obase + w0) = st;
        }
    }
}

// ---------- depthwise 3x3 reflect-pad + bias + LeakyReLU, out += result (bf16 h2) ----------
// 8 outputs/thread, vectorized row loads, XCD-chunk-swizzled.
__global__ __launch_bounds__(256) void dw_v2(const __hip_bfloat16* __restrict__ h2,
                                             const float* __restrict__ dww,
                                             const float* __restrict__ dwb,
                                             float* __restrict__ out) {
    int bid = blockIdx.x;                          // 8192 blocks
    int swz = (bid & 7) * 1024 + (bid >> 3);
    size_t tidx = (size_t)swz * 256 + threadIdx.x; // 2097152 threads total
    int w0 = (int)((tidx & 15) << 3);
    int hh = (int)((tidx >> 4) & 127);
    int bc = (int)(tidx >> 11);
    int c  = bc & 127;
    const __hip_bfloat16* src = h2 + ((size_t)bc << 14);
    float wg[9];
#pragma unroll
    for (int k = 0; k < 9; ++k) wg[k] = dww[c * 9 + k];
    float bv = dwb[c];
    float a8[8];
#pragma unroll
    for (int j = 0; j < 8; ++j) a8[j] = bv;
#pragma unroll
    for (int kh = 0; kh < 3; ++kh) {
        int ih = hh + kh - 1;
        ih = ih < 0 ? 1 : (ih > 127 ? 126 : ih);
        const __hip_bfloat16* row = src + ih * 128;
        short8 mid = *reinterpret_cast<const short8*>(row + w0);
        float v[10];
        v[0] = bf2f(row[w0 == 0 ? 1 : w0 - 1]);
#pragma unroll
        for (int j = 0; j < 8; ++j)
            v[j + 1] = __uint_as_float((unsigned int)(unsigned short)mid[j] << 16);
        v[9] = bf2f(row[w0 == 120 ? 126 : w0 + 8]);
#pragma unroll
        for (int kw = 0; kw < 3; ++kw)
#pragma unroll
            for (int j = 0; j < 8; ++j)
                a8[j] = fmaf(v[j + kw], wg[kh * 3 + kw], a8[j]);
    }
    size_t ob = ((size_t)bc << 14) + hh * 128 + w0;
    float4 o0 = *reinterpret_cast<const float4*>(out + ob);
    float4 o1 = *reinterpret_cast<const float4*>(out + ob + 4);
#pragma unroll
    for (int j = 0; j < 8; ++j) a8[j] = a8[j] >= 0.f ? a8[j] : SLOPE * a8[j];
    o0.x += a8[0]; o0.y += a8[1]; o0.z += a8[2]; o0.w += a8[3];
    o1.x += a8[4]; o1.y += a8[5]; o1.z += a8[6]; o1.w += a8[7];
    *reinterpret_cast<float4*>(out + ob) = o0;
    *reinterpret_cast<float4*>(out + ob + 4) = o1;
}

extern "C" void kernel_launch(void* const* d_in, const int* in_sizes, int n_in,
                              void* d_out, int out_size, void* d_ws, size_t ws_size,
                              hipStream_t stream) {
    const float* x1   = (const float*)d_in[0];
    const float* x2   = (const float*)d_in[1];
    const float* temp = (const float*)d_in[2];
    const float* c1w  = (const float*)d_in[3];
    const float* c1b  = (const float*)d_in[4];
    const float* c2w  = (const float*)d_in[5];
    const float* c2b  = (const float*)d_in[6];
    const float* dww  = (const float*)d_in[7];
    const float* dwb  = (const float*)d_in[8];
    const float* scw  = (const float*)d_in[9];
    const float* scb  = (const float*)d_in[10];
    float* out = (float*)d_out;
    char* ws = (char*)d_ws;

    float*          G    = (float*)(ws);                        // 32 KB
    float*          attn = (float*)(ws + (32 << 10));           // 32 KB
    float*          Gp   = (float*)(ws + (64 << 10));           // 128 KB
    __hip_bfloat16* wb1  = (__hip_bfloat16*)(ws + (192 << 10)); // 288 KB (frag-major, quartered)
    __hip_bfloat16* wb2  = (__hip_bfloat16*)(ws + (480 << 10)); // 32 KB  (frag-major)
    __hip_bfloat16* wbsc = (__hip_bfloat16*)(ws + (512 << 10)); // 32 KB  (frag-major)
    __hip_bfloat16* yt   = (__hip_bfloat16*)(ws + ((size_t)1 << 20));   // 32 MiB NHWC bf16
    __hip_bfloat16* h2b  = (__hip_bfloat16*)(ws + ((size_t)34 << 20));  // 32 MiB NCHW bf16

    prep_wb1<<<576, 256, 0, stream>>>(c1w, wb1);
    prep_w1x1<<<64, 256, 0, stream>>>(c2w, wb2);
    prep_w1x1<<<64, 256, 0, stream>>>(scw, wbsc);

    gram_part<<<512, 256, 0, stream>>>(x1, Gp);
    gram_reduce<<<128, 64, 0, stream>>>(Gp, G);
    softmax_kernel<<<128, 64, 0, stream>>>(G, temp, attn);
    av_v2<<<2048, 256, 0, stream>>>(x2, attn, yt);

    fused_conv<<<1024, 256, 0, stream>>>(yt, wb1, wb2, wbsc, c1b, c2b, scb, x1, h2b, out);
    dw_v2<<<8192, 256, 0, stream>>>(h2b, dww, dwb, out);
}